// Round 10
// baseline (634.712 us; speedup 1.0000x reference)
//
#include <hip/hip_runtime.h>
#include <hip/hip_bf16.h>

#define N_NODES 50000
#define N_EDGES 1600000
#define NG      256
#define HD      128
#define NBUCKET 782          // dst >> 6 (64 nodes per bucket)
#define NPB     64           // nodes per bucket
#define EPB     4096         // edges per block in hist/scatter
#define NBA     391          // ceil(N_EDGES / EPB)
#define OFFS_LD 392          // leading dim of offsG
#define LDSP    136          // padded LDS row (bf16)

typedef __attribute__((ext_vector_type(8))) __bf16 bf16x8;
typedef __attribute__((ext_vector_type(4))) float f32x4;
typedef unsigned int uint;

__device__ __forceinline__ float bf_lo(uint u) { return __uint_as_float(u << 16); }
__device__ __forceinline__ float bf_hi(uint u) { return __uint_as_float(u & 0xFFFF0000u); }

// ---------------- bucket histogram ----------------

__global__ __launch_bounds__(256) void bhist_kernel(const int* __restrict__ dst,
                                                    int* __restrict__ histG) {
    __shared__ int hist[NBUCKET];
    int b = blockIdx.x, t = threadIdx.x;
    for (int i = t; i < NBUCKET; i += 256) hist[i] = 0;
    __syncthreads();
    int e0 = b * EPB;
    #pragma unroll
    for (int i = 0; i < 16; ++i) {
        int e = e0 + i * 256 + t;
        if (e < N_EDGES) atomicAdd(&hist[dst[e] >> 6], 1);
    }
    __syncthreads();
    for (int i = t; i < NBUCKET; i += 256) histG[b * NBUCKET + i] = hist[i];
}

// ---------------- per-bucket scan over blocks: offsG[bucket][block], bucket_tot ----------------

__global__ __launch_bounds__(256) void scanb_kernel(const int* __restrict__ histG,
                                                    int* __restrict__ offsG,
                                                    int* __restrict__ bucket_tot) {
    __shared__ int sh[256];
    int bucket = blockIdx.x, t = threadIdx.x;
    int k0 = 2 * t, k1 = 2 * t + 1;
    int a0 = (k0 < NBA) ? histG[k0 * NBUCKET + bucket] : 0;
    int a1 = (k1 < NBA) ? histG[k1 * NBUCKET + bucket] : 0;
    int pair = a0 + a1;
    sh[t] = pair;
    __syncthreads();
    for (int off = 1; off < 256; off <<= 1) {
        int x = (t >= off) ? sh[t - off] : 0;
        __syncthreads();
        sh[t] += x;
        __syncthreads();
    }
    int excl = sh[t] - pair;
    if (k0 < NBA) offsG[bucket * OFFS_LD + k0] = excl;
    if (k1 < NBA) offsG[bucket * OFFS_LD + k1] = excl + a0;
    if (t == 255) bucket_tot[bucket] = sh[255];
}

// ---------------- scan bucket totals (1024-wide: 256 thr x 4) ----------------

__global__ __launch_bounds__(256) void scanbase_kernel(const int* __restrict__ tot,
                                                       int* __restrict__ base) {
    __shared__ int sh[256];
    int t = threadIdx.x;
    int b0 = t * 4;
    int v0 = (b0 + 0 < NBUCKET) ? tot[b0 + 0] : 0;
    int v1 = (b0 + 1 < NBUCKET) ? tot[b0 + 1] : 0;
    int v2 = (b0 + 2 < NBUCKET) ? tot[b0 + 2] : 0;
    int v3 = (b0 + 3 < NBUCKET) ? tot[b0 + 3] : 0;
    int s3 = v0 + v1 + v2 + v3;
    sh[t] = s3;
    __syncthreads();
    for (int off = 1; off < 256; off <<= 1) {
        int x = (t >= off) ? sh[t - off] : 0;
        __syncthreads();
        sh[t] += x;
        __syncthreads();
    }
    int run = sh[t] - s3;
    if (b0 + 0 < NBUCKET) base[b0 + 0] = run;
    run += v0;
    if (b0 + 1 < NBUCKET) base[b0 + 1] = run;
    run += v1;
    if (b0 + 2 < NBUCKET) base[b0 + 2] = run;
    run += v2;
    if (b0 + 3 < NBUCKET) base[b0 + 3] = run;
    if (t == 255) base[NBUCKET] = sh[255];
}

// ---------------- scatter into bucket-grouped packed array ----------------
// packed[e] = (dst&63)<<16 | src   (src < 65536)

__global__ __launch_bounds__(256) void scatter_kernel(const int* __restrict__ src,
                                                      const int* __restrict__ dst,
                                                      const int* __restrict__ base,
                                                      const int* __restrict__ offsG,
                                                      uint* __restrict__ packed) {
    __shared__ int cur[NBUCKET];
    int b = blockIdx.x, t = threadIdx.x;
    for (int i = t; i < NBUCKET; i += 256) cur[i] = base[i] + offsG[i * OFFS_LD + b];
    __syncthreads();
    int e0 = b * EPB;
    #pragma unroll
    for (int i = 0; i < 16; ++i) {
        int e = e0 + i * 256 + t;
        if (e < N_EDGES) {
            int d = dst[e];
            int s = src[e];
            int pos = atomicAdd(&cur[d >> 6], 1);
            packed[pos] = ((uint)(d & 63) << 16) | (uint)s;
        }
    }
}

// ---------------- per-bucket CSR finalize (782 blocks, 64 nodes each) ----------------

__global__ __launch_bounds__(256) void csr_bucket_kernel(const uint* __restrict__ packed,
                                                         const int* __restrict__ base,
                                                         int* __restrict__ row_ptr,
                                                         float* __restrict__ degInv,
                                                         int* __restrict__ col) {
    __shared__ int cnt[NPB];
    __shared__ int sh[NPB];
    __shared__ int cur[NPB];
    int bucket = blockIdx.x, t = threadIdx.x;
    if (t < NPB) cnt[t] = 0;
    __syncthreads();
    int s = base[bucket], e = base[bucket + 1];
    for (int j = s + t; j < e; j += 256) atomicAdd(&cnt[packed[j] >> 16], 1);
    __syncthreads();
    int v = 0;
    if (t < NPB) { v = cnt[t]; sh[t] = v; }
    __syncthreads();
    for (int off = 1; off < NPB; off <<= 1) {
        int x = 0;
        if (t < NPB && t >= off) x = sh[t - off];
        __syncthreads();
        if (t < NPB) sh[t] += x;
        __syncthreads();
    }
    if (t < NPB) {
        int excl = sh[t] - v;
        int id = bucket * NPB + t;
        if (id < N_NODES) {
            row_ptr[id] = s + excl;
            degInv[id] = 1.0f / fmaxf((float)v, 1.0f);
            if (id == N_NODES - 1) row_ptr[N_NODES] = e;
        }
        cur[t] = s + excl;
    }
    __syncthreads();
    for (int j = s + t; j < e; j += 256) {
        uint pk = packed[j];
        int dl = (int)(pk >> 16);
        int pos = atomicAdd(&cur[dl], 1);
        col[pos] = (int)(pk & 0xFFFFu);
    }
}

// ---------------- fp32 -> bf16 cast of x ----------------

__global__ void cast_x_kernel(const float* __restrict__ x, __hip_bfloat16* __restrict__ xb) {
    int i = blockIdx.x * 256 + threadIdx.x;
    if (i < N_NODES * 32) {
        float4 v = ((const float4*)x)[i];
        float2 lo = {v.x, v.y}, hi = {v.z, v.w};
        ((__hip_bfloat162*)xb)[i * 2 + 0] = __float22bfloat162_rn(lo);
        ((__hip_bfloat162*)xb)[i * 2 + 1] = __float22bfloat162_rn(hi);
    }
}

// ---------------- weight pack (MFMA B-frag-linear layout) ----------------
// k = kk*32 + (lane>>4)*8 + i, col = n*16 + (lane&15); A/B share slot->k map.

__global__ void pack_w_kernel(const float* __restrict__ p0a, const float* __restrict__ p0b,
                              const float* __restrict__ p1a, const float* __restrict__ p1b,
                              const float* __restrict__ p2a, const float* __restrict__ p2b,
                              const float* __restrict__ p3a, const float* __restrict__ p3b,
                              const float* __restrict__ p4a, const float* __restrict__ p4b,
                              const float* __restrict__ p5a, const float* __restrict__ p5b,
                              __hip_bfloat16* __restrict__ out) {
    int idx = blockIdx.x * 256 + threadIdx.x;
    if (idx >= 6 * 32768) return;
    int g = idx >> 15;
    int r = idx & 32767;
    int i = r & 7;
    int k = ((r >> 12) & 7) * 32 + ((r >> 7) & 3) * 8 + i;
    int c = ((r >> 9) & 7) * 16 + ((r >> 3) & 15);
    const float* a; const float* b;
    switch (g) {
        case 0: a = p0a; b = p0b; break;
        case 1: a = p1a; b = p1b; break;
        case 2: a = p2a; b = p2b; break;
        case 3: a = p3a; b = p3b; break;
        case 4: a = p4a; b = p4b; break;
        default: a = p5a; b = p5b; break;
    }
    const float* srcp = (k < 128) ? a : b;
    int kk2 = k & 127;
    out[idx] = __float2bfloat16(srcp[kk2 * HD + c]);
}

// ---------------- mean aggregation: XCD-sliced wave-per-node ----------------
// block b: slice = (b>>1)&3 (constant per XCD under round-robin b%8->XCD),
// nodes = (((b>>3)<<1)|(b&1))*4 + wave. Each XCD's X working set = 3.2 MB slice.
// Wave: 16 edge-groups x 4 dim-octet lanes (16B each), shfl-reduce, 64B store.

__global__ __launch_bounds__(256) void agg_kernel(const __hip_bfloat16* __restrict__ X,
                                                  const int* __restrict__ row_ptr,
                                                  const int* __restrict__ col,
                                                  const float* __restrict__ degInv,
                                                  __hip_bfloat16* __restrict__ out) {
    int b = blockIdx.x;
    int wave = threadIdx.x >> 6;
    int lane = threadIdx.x & 63;
    int slice = (b >> 1) & 3;
    int nb = ((b >> 3) << 1) | (b & 1);
    int node = nb * 4 + wave;            // < 50000 by construction
    int beg = row_ptr[node], end = row_ptr[node + 1];
    int g = lane >> 2;                   // edge subgroup 0..15
    int p = lane & 3;                    // dim octet within slice
    const __hip_bfloat16* __restrict__ Xs = X + slice * 32 + p * 8;
    float acc[8] = {};
    #pragma unroll 2
    for (int j = beg + g; j < end; j += 16) {
        int s = col[j];
        uint4 v = *(const uint4*)&Xs[(size_t)s * HD];
        acc[0] += bf_lo(v.x); acc[1] += bf_hi(v.x);
        acc[2] += bf_lo(v.y); acc[3] += bf_hi(v.y);
        acc[4] += bf_lo(v.z); acc[5] += bf_hi(v.z);
        acc[6] += bf_lo(v.w); acc[7] += bf_hi(v.w);
    }
    #pragma unroll
    for (int k = 0; k < 8; ++k) {
        acc[k] += __shfl_xor(acc[k], 4, 64);
        acc[k] += __shfl_xor(acc[k], 8, 64);
        acc[k] += __shfl_xor(acc[k], 16, 64);
        acc[k] += __shfl_xor(acc[k], 32, 64);
    }
    if (lane < 4) {
        float inv = degInv[node];
        uint ow[4];
        #pragma unroll
        for (int k = 0; k < 4; ++k) {
            float2 vv = {acc[2 * k] * inv, acc[2 * k + 1] * inv};
            union { __hip_bfloat162 h; uint u; } cv;
            cv.h = __float22bfloat162_rn(vv);
            ow[k] = cv.u;
        }
        *(uint4*)&out[(size_t)node * HD + slice * 32 + p * 8] = make_uint4(ow[0], ow[1], ow[2], ow[3]);
    }
}

// ---------------- dual-matmul via MFMA: out = relu([A1|A2]@Bp + b) ----------------

__global__ __launch_bounds__(256) void gemm_mfma_kernel(
        const __hip_bfloat16* __restrict__ A1, const __hip_bfloat16* __restrict__ A2,
        const __hip_bfloat16* __restrict__ Bp, const float* __restrict__ bias,
        __hip_bfloat16* __restrict__ out) {
    int lane = threadIdx.x & 63;
    int wave = threadIdx.x >> 6;
    int row0 = blockIdx.x * 64 + wave * 16;
    int arow = row0 + (lane & 15);
    int arow_c = min(arow, N_NODES - 1);
    int kb = (lane >> 4) << 3;
    f32x4 acc[8] = {};
    const bf16x8* __restrict__ Bp8 = (const bf16x8*)Bp;
    #pragma unroll
    for (int kk = 0; kk < 8; ++kk) {
        const __hip_bfloat16* __restrict__ As = (kk < 4) ? A1 : A2;
        int k0 = (kk & 3) * 32 + kb;
        bf16x8 af = *(const bf16x8*)&As[(size_t)arow_c * HD + k0];
        #pragma unroll
        for (int n = 0; n < 8; ++n) {
            bf16x8 bf = Bp8[(kk * 8 + n) * 64 + lane];
            acc[n] = __builtin_amdgcn_mfma_f32_16x16x32_bf16(af, bf, acc[n], 0, 0, 0);
        }
    }
    int crow0 = row0 + ((lane >> 4) << 2);
    int ccol = lane & 15;
    #pragma unroll
    for (int n = 0; n < 8; ++n) {
        int c = n * 16 + ccol;
        float bv = bias[c];
        #pragma unroll
        for (int i = 0; i < 4; ++i) {
            int row = crow0 + i;
            if (row < N_NODES) {
                float v = acc[n][i] + bv;
                out[(size_t)row * HD + c] = __float2bfloat16(fmaxf(v, 0.f));
            }
        }
    }
}

// ---------------- fused h2-GEMM + JK linear (4 self-contained waves, no barriers) ----------------

__global__ __launch_bounds__(256) void gemm2jk_kernel(
        const __hip_bfloat16* __restrict__ A, const __hip_bfloat16* __restrict__ H1,
        const __hip_bfloat16* __restrict__ BpS, const float* __restrict__ b2,
        const __hip_bfloat16* __restrict__ BpJ, const float* __restrict__ bjk,
        __hip_bfloat16* __restrict__ out) {
    __shared__ __hip_bfloat16 As[64][LDSP];
    int lane = threadIdx.x & 63;
    int wave = threadIdx.x >> 6;
    int row0 = blockIdx.x * 64 + wave * 16;
    int arow_c = min(row0 + (lane & 15), N_NODES - 1);
    int lrow = wave * 16 + (lane & 15);
    int kb = (lane >> 4) << 3;
    const bf16x8* __restrict__ BpS8 = (const bf16x8*)BpS;
    const bf16x8* __restrict__ BpJ8 = (const bf16x8*)BpJ;

    // phase B: h2 tile = relu(A@Wl2 + H1@Wr2 + b2)
    f32x4 acc[8] = {};
    #pragma unroll
    for (int kk = 0; kk < 8; ++kk) {
        const __hip_bfloat16* __restrict__ Asrc = (kk < 4) ? A : H1;
        int k0 = (kk & 3) * 32 + kb;
        bf16x8 af = *(const bf16x8*)&Asrc[(size_t)arow_c * HD + k0];
        #pragma unroll
        for (int n = 0; n < 8; ++n) {
            bf16x8 bf = BpS8[(kk * 8 + n) * 64 + lane];
            acc[n] = __builtin_amdgcn_mfma_f32_16x16x32_bf16(af, bf, acc[n], 0, 0, 0);
        }
    }
    // phase C: stash h2 into this wave's own LDS rows
    int crl0 = wave * 16 + ((lane >> 4) << 2);
    int ccol = lane & 15;
    #pragma unroll
    for (int n = 0; n < 8; ++n) {
        int c = n * 16 + ccol;
        float bv = b2[c];
        #pragma unroll
        for (int i = 0; i < 4; ++i) {
            float v = fmaxf(acc[n][i] + bv, 0.f);
            As[crl0 + i][c] = __float2bfloat16(v);
        }
    }
    // phase D: JK GEMM (k<128: H1 self from global; k>=128: h2 from LDS)
    f32x4 acc2[8] = {};
    #pragma unroll
    for (int kk = 0; kk < 8; ++kk) {
        int k0 = (kk & 3) * 32 + kb;
        bf16x8 af = (kk < 4) ? *(const bf16x8*)&H1[(size_t)arow_c * HD + k0]
                             : *(const bf16x8*)&As[lrow][k0];
        #pragma unroll
        for (int n = 0; n < 8; ++n) {
            bf16x8 bf = BpJ8[(kk * 8 + n) * 64 + lane];
            acc2[n] = __builtin_amdgcn_mfma_f32_16x16x32_bf16(af, bf, acc2[n], 0, 0, 0);
        }
    }
    int crow0 = row0 + ((lane >> 4) << 2);
    #pragma unroll
    for (int n = 0; n < 8; ++n) {
        int c = n * 16 + ccol;
        float bv = bjk[c];
        #pragma unroll
        for (int i = 0; i < 4; ++i) {
            int row = crow0 + i;
            if (row < N_NODES) {
                float v = acc2[n][i] + bv;
                out[(size_t)row * HD + c] = __float2bfloat16(fmaxf(v, 0.f));
            }
        }
    }
}

// ---------------- pooling: node-chunk blocks + run-merged atomics ----------------

__global__ __launch_bounds__(128) void pool_kernel(const __hip_bfloat16* __restrict__ h,
                                                   const int* __restrict__ batch,
                                                   float* __restrict__ p) {
    __shared__ int bsh[32];
    int n0 = blockIdx.x * 32, t = threadIdx.x;
    if (t < 32) bsh[t] = (n0 + t < N_NODES) ? batch[n0 + t] : -1;
    __syncthreads();
    float run = 0.f;
    int gprev = bsh[0];
    for (int r = 0; r < 32; ++r) {
        int n = n0 + r;
        if (n >= N_NODES) break;
        int g = bsh[r];
        float v = __bfloat162float(h[(size_t)n * HD + t]);
        if (g != gprev) {
            atomicAdd(&p[gprev * HD + t], run);
            run = 0.f;
            gprev = g;
        }
        run += v;
    }
    if (gprev >= 0) atomicAdd(&p[gprev * HD + t], run);
}

// ---------------- head: BN + MLP + softmax ----------------

__global__ void head_kernel(const float* __restrict__ p0, const float* __restrict__ p1,
                            const float* __restrict__ gamma, const float* __restrict__ beta,
                            const float* __restrict__ rm, const float* __restrict__ rv,
                            const float* __restrict__ W1, const float* __restrict__ b1,
                            const float* __restrict__ W2, const float* __restrict__ b2,
                            float* __restrict__ out) {
    __shared__ float xb[256];
    __shared__ float hh[128];
    __shared__ float oo[10];
    int g = blockIdx.x, t = threadIdx.x;  // 128 threads
    {
        float v0 = p0[g * HD + t];
        float v1 = p1[g * HD + t];
        int d1 = t + 128;
        xb[t]  = (v0 - rm[t])  * rsqrtf(rv[t]  + 1e-5f) * gamma[t]  + beta[t];
        xb[d1] = (v1 - rm[d1]) * rsqrtf(rv[d1] + 1e-5f) * gamma[d1] + beta[d1];
    }
    __syncthreads();
    float acc = b1[t];
    for (int d = 0; d < 256; ++d) acc += xb[d] * W1[d * HD + t];
    hh[t] = fmaxf(acc, 0.f);
    __syncthreads();
    if (t < 10) {
        float o = b2[t];
        for (int d = 0; d < 128; ++d) o += hh[d] * W2[d * 10 + t];
        oo[t] = o;
    }
    __syncthreads();
    if (t < 10) {
        float m = oo[0];
        for (int c = 1; c < 10; ++c) m = fmaxf(m, oo[c]);
        float sum = 0.f;
        for (int c = 0; c < 10; ++c) sum += expf(oo[c] - m);
        out[g * 10 + t] = expf(oo[t] - m) / sum;
    }
}

// ---------------- launcher ----------------

extern "C" void kernel_launch(void* const* d_in, const int* in_sizes, int n_in,
                              void* d_out, int out_size, void* d_ws, size_t ws_size,
                              hipStream_t stream) {
    const float* x     = (const float*)d_in[0];
    const int*   ei    = (const int*)d_in[1];
    const int*   batch = (const int*)d_in[2];
    const int*   src = ei;
    const int*   dst = ei + N_EDGES;

    const float* b0_Wl1 = (const float*)d_in[4];
    const float* b0_Wr1 = (const float*)d_in[5];
    const float* b0_b1  = (const float*)d_in[6];
    const float* b0_Wl2 = (const float*)d_in[7];
    const float* b0_Wr2 = (const float*)d_in[8];
    const float* b0_b2  = (const float*)d_in[9];
    const float* b0_Wlin = (const float*)d_in[10];
    const float* b0_blin = (const float*)d_in[11];
    const float* b1_Wl1 = (const float*)d_in[12];
    const float* b1_Wr1 = (const float*)d_in[13];
    const float* b1_b1  = (const float*)d_in[14];
    const float* b1_Wl2 = (const float*)d_in[15];
    const float* b1_Wr2 = (const float*)d_in[16];
    const float* b1_b2  = (const float*)d_in[17];
    const float* b1_Wlin = (const float*)d_in[18];
    const float* b1_blin = (const float*)d_in[19];
    const float* bn_gamma = (const float*)d_in[20];
    const float* bn_beta  = (const float*)d_in[21];
    const float* bn_rm    = (const float*)d_in[22];
    const float* bn_rv    = (const float*)d_in[23];
    const float* lin1_W = (const float*)d_in[24];
    const float* lin1_b = (const float*)d_in[25];
    const float* lin2_W = (const float*)d_in[26];
    const float* lin2_b = (const float*)d_in[27];

    float* out = (float*)d_out;

    char* ws = (char*)d_ws;
    size_t off = 0;
    auto alloc = [&](size_t bytes) { void* p = ws + off; off += (bytes + 255) & ~size_t(255); return p; };
    int* histG      = (int*)alloc((size_t)NBA * NBUCKET * 4);
    int* offsG      = (int*)alloc((size_t)NBUCKET * OFFS_LD * 4);
    int* bucket_tot = (int*)alloc(NBUCKET * 4);
    int* bucket_base= (int*)alloc((NBUCKET + 1) * 4);
    uint* packed    = (uint*)alloc((size_t)N_EDGES * 4);
    int* col        = (int*)alloc((size_t)N_EDGES * 4);
    int* row_ptr    = (int*)alloc((N_NODES + 1) * 4);
    float* degInv   = (float*)alloc((size_t)N_NODES * 4);
    __hip_bfloat16* Xb = (__hip_bfloat16*)alloc((size_t)N_NODES * HD * 2);
    __hip_bfloat16* A  = (__hip_bfloat16*)alloc((size_t)N_NODES * HD * 2);
    __hip_bfloat16* B  = (__hip_bfloat16*)alloc((size_t)N_NODES * HD * 2);
    __hip_bfloat16* D  = (__hip_bfloat16*)alloc((size_t)N_NODES * HD * 2);
    __hip_bfloat16* Bpack = (__hip_bfloat16*)alloc(6 * 32768 * 2);
    float* p0 = (float*)alloc(NG * HD * 4);
    float* p1 = (float*)alloc(NG * HD * 4);
    (void)ws_size; (void)n_in; (void)in_sizes; (void)out_size;

    // ---- CSR build via bucket sort (no global atomics) ----
    bhist_kernel<<<NBA, 256, 0, stream>>>(dst, histG);
    scanb_kernel<<<NBUCKET, 256, 0, stream>>>(histG, offsG, bucket_tot);
    scanbase_kernel<<<1, 256, 0, stream>>>(bucket_tot, bucket_base);
    scatter_kernel<<<NBA, 256, 0, stream>>>(src, dst, bucket_base, offsG, packed);
    csr_bucket_kernel<<<NBUCKET, 256, 0, stream>>>(packed, bucket_base, row_ptr, degInv, col);

    cast_x_kernel<<<(N_NODES * 32 + 255) / 256, 256, 0, stream>>>(x, Xb);
    pack_w_kernel<<<(6 * 32768 + 255) / 256, 256, 0, stream>>>(
        b0_Wl1, b0_Wr1, b0_Wl2, b0_Wr2, b0_Wlin, b0_Wlin + 128 * HD,
        b1_Wl1, b1_Wr1, b1_Wl2, b1_Wr2, b1_Wlin, b1_Wlin + 128 * HD, Bpack);
    hipMemsetAsync(p0, 0, 2 * NG * HD * 4, stream);  // p0,p1 contiguous

    const int AGG_B = N_NODES;   // 50000 blocks: 4 slices x 12500 node-quads
    const int GEMM_B = (N_NODES + 63) / 64;
    const int POOL_B = (N_NODES + 31) / 32;

    __hip_bfloat16* Bp0 = Bpack + 0 * 32768;
    __hip_bfloat16* Bp1 = Bpack + 1 * 32768;
    __hip_bfloat16* Bp2 = Bpack + 2 * 32768;
    __hip_bfloat16* Bp3 = Bpack + 3 * 32768;
    __hip_bfloat16* Bp4 = Bpack + 4 * 32768;
    __hip_bfloat16* Bp5 = Bpack + 5 * 32768;

    // block 0
    agg_kernel<<<AGG_B, 256, 0, stream>>>(Xb, row_ptr, col, degInv, A);
    gemm_mfma_kernel<<<GEMM_B, 256, 0, stream>>>(A, Xb, Bp0, b0_b1, B);            // h1
    agg_kernel<<<AGG_B, 256, 0, stream>>>(B, row_ptr, col, degInv, A);
    gemm2jk_kernel<<<GEMM_B, 256, 0, stream>>>(A, B, Bp1, b0_b2, Bp2, b0_blin, D); // h2+JK
    pool_kernel<<<POOL_B, 128, 0, stream>>>(D, batch, p0);
    // block 1
    agg_kernel<<<AGG_B, 256, 0, stream>>>(D, row_ptr, col, degInv, A);
    gemm_mfma_kernel<<<GEMM_B, 256, 0, stream>>>(A, D, Bp3, b1_b1, B);             // h1
    agg_kernel<<<AGG_B, 256, 0, stream>>>(B, row_ptr, col, degInv, A);
    gemm2jk_kernel<<<GEMM_B, 256, 0, stream>>>(A, B, Bp4, b1_b2, Bp5, b1_blin, D); // h2+JK
    pool_kernel<<<POOL_B, 128, 0, stream>>>(D, batch, p1);
    // head
    head_kernel<<<NG, HD, 0, stream>>>(p0, p1, bn_gamma, bn_beta, bn_rm, bn_rv,
                                       lin1_W, lin1_b, lin2_W, lin2_b, out);
}

// Round 11
// 544.758 us; speedup vs baseline: 1.1651x; 1.1651x over previous
//
#include <hip/hip_runtime.h>
#include <hip/hip_bf16.h>

#define N_NODES 50000
#define N_EDGES 1600000
#define NG      256
#define HD      128
#define NBUCKET 782          // dst >> 6 (64 nodes per bucket)
#define NPB     64           // nodes per bucket
#define EPB     4096         // edges per block in hist/scatter
#define NBA     391          // ceil(N_EDGES / EPB)
#define OFFS_LD 392          // leading dim of offsG
#define LDSP    136          // padded LDS row (bf16)
#define CAST_B  6250         // blocks of prep doing cast (50000*32/256)
#define PACK_B  768          // blocks of prep doing weight pack (6*32768/256)

typedef __attribute__((ext_vector_type(8))) __bf16 bf16x8;
typedef __attribute__((ext_vector_type(4))) float f32x4;
typedef unsigned int uint;

__device__ __forceinline__ float bf_lo(uint u) { return __uint_as_float(u << 16); }
__device__ __forceinline__ float bf_hi(uint u) { return __uint_as_float(u & 0xFFFF0000u); }

// ---------------- bucket histogram ----------------

__global__ __launch_bounds__(256) void bhist_kernel(const int* __restrict__ dst,
                                                    int* __restrict__ histG) {
    __shared__ int hist[NBUCKET];
    int b = blockIdx.x, t = threadIdx.x;
    for (int i = t; i < NBUCKET; i += 256) hist[i] = 0;
    __syncthreads();
    int e0 = b * EPB;
    #pragma unroll
    for (int i = 0; i < 16; ++i) {
        int e = e0 + i * 256 + t;
        if (e < N_EDGES) atomicAdd(&hist[dst[e] >> 6], 1);
    }
    __syncthreads();
    for (int i = t; i < NBUCKET; i += 256) histG[b * NBUCKET + i] = hist[i];
}

// ---------------- per-bucket scan over blocks: offsG[bucket][block], bucket_tot ----------------

__global__ __launch_bounds__(256) void scanb_kernel(const int* __restrict__ histG,
                                                    int* __restrict__ offsG,
                                                    int* __restrict__ bucket_tot) {
    __shared__ int sh[256];
    int bucket = blockIdx.x, t = threadIdx.x;
    int k0 = 2 * t, k1 = 2 * t + 1;
    int a0 = (k0 < NBA) ? histG[k0 * NBUCKET + bucket] : 0;
    int a1 = (k1 < NBA) ? histG[k1 * NBUCKET + bucket] : 0;
    int pair = a0 + a1;
    sh[t] = pair;
    __syncthreads();
    for (int off = 1; off < 256; off <<= 1) {
        int x = (t >= off) ? sh[t - off] : 0;
        __syncthreads();
        sh[t] += x;
        __syncthreads();
    }
    int excl = sh[t] - pair;
    if (k0 < NBA) offsG[bucket * OFFS_LD + k0] = excl;
    if (k1 < NBA) offsG[bucket * OFFS_LD + k1] = excl + a0;
    if (t == 255) bucket_tot[bucket] = sh[255];
}

// ---------------- scan bucket totals (1024-wide: 256 thr x 4) ----------------

__global__ __launch_bounds__(256) void scanbase_kernel(const int* __restrict__ tot,
                                                       int* __restrict__ base) {
    __shared__ int sh[256];
    int t = threadIdx.x;
    int b0 = t * 4;
    int v0 = (b0 + 0 < NBUCKET) ? tot[b0 + 0] : 0;
    int v1 = (b0 + 1 < NBUCKET) ? tot[b0 + 1] : 0;
    int v2 = (b0 + 2 < NBUCKET) ? tot[b0 + 2] : 0;
    int v3 = (b0 + 3 < NBUCKET) ? tot[b0 + 3] : 0;
    int s3 = v0 + v1 + v2 + v3;
    sh[t] = s3;
    __syncthreads();
    for (int off = 1; off < 256; off <<= 1) {
        int x = (t >= off) ? sh[t - off] : 0;
        __syncthreads();
        sh[t] += x;
        __syncthreads();
    }
    int run = sh[t] - s3;
    if (b0 + 0 < NBUCKET) base[b0 + 0] = run;
    run += v0;
    if (b0 + 1 < NBUCKET) base[b0 + 1] = run;
    run += v1;
    if (b0 + 2 < NBUCKET) base[b0 + 2] = run;
    run += v2;
    if (b0 + 3 < NBUCKET) base[b0 + 3] = run;
    if (t == 255) base[NBUCKET] = sh[255];
}

// ---------------- scatter into bucket-grouped packed array ----------------
// packed[e] = (dst&63)<<16 | src   (src < 65536)

__global__ __launch_bounds__(256) void scatter_kernel(const int* __restrict__ src,
                                                      const int* __restrict__ dst,
                                                      const int* __restrict__ base,
                                                      const int* __restrict__ offsG,
                                                      uint* __restrict__ packed) {
    __shared__ int cur[NBUCKET];
    int b = blockIdx.x, t = threadIdx.x;
    for (int i = t; i < NBUCKET; i += 256) cur[i] = base[i] + offsG[i * OFFS_LD + b];
    __syncthreads();
    int e0 = b * EPB;
    #pragma unroll
    for (int i = 0; i < 16; ++i) {
        int e = e0 + i * 256 + t;
        if (e < N_EDGES) {
            int d = dst[e];
            int s = src[e];
            int pos = atomicAdd(&cur[d >> 6], 1);
            packed[pos] = ((uint)(d & 63) << 16) | (uint)s;
        }
    }
}

// ---------------- per-bucket CSR finalize (782 blocks, 64 nodes each) ----------------

__global__ __launch_bounds__(256) void csr_bucket_kernel(const uint* __restrict__ packed,
                                                         const int* __restrict__ base,
                                                         int* __restrict__ row_ptr,
                                                         float* __restrict__ degInv,
                                                         int* __restrict__ col) {
    __shared__ int cnt[NPB];
    __shared__ int sh[NPB];
    __shared__ int cur[NPB];
    int bucket = blockIdx.x, t = threadIdx.x;
    if (t < NPB) cnt[t] = 0;
    __syncthreads();
    int s = base[bucket], e = base[bucket + 1];
    for (int j = s + t; j < e; j += 256) atomicAdd(&cnt[packed[j] >> 16], 1);
    __syncthreads();
    int v = 0;
    if (t < NPB) { v = cnt[t]; sh[t] = v; }
    __syncthreads();
    for (int off = 1; off < NPB; off <<= 1) {
        int x = 0;
        if (t < NPB && t >= off) x = sh[t - off];
        __syncthreads();
        if (t < NPB) sh[t] += x;
        __syncthreads();
    }
    if (t < NPB) {
        int excl = sh[t] - v;
        int id = bucket * NPB + t;
        if (id < N_NODES) {
            row_ptr[id] = s + excl;
            degInv[id] = 1.0f / fmaxf((float)v, 1.0f);
            if (id == N_NODES - 1) row_ptr[N_NODES] = e;
        }
        cur[t] = s + excl;
    }
    __syncthreads();
    for (int j = s + t; j < e; j += 256) {
        uint pk = packed[j];
        int dl = (int)(pk >> 16);
        int pos = atomicAdd(&cur[dl], 1);
        col[pos] = (int)(pk & 0xFFFFu);
    }
}

// ---------------- prep: x cast (blocks < CAST_B) + weight pack (rest) ----------------
// pack layout: k = kk*32 + (lane>>4)*8 + i, col = n*16 + (lane&15).

__global__ __launch_bounds__(256) void prep_kernel(
        const float* __restrict__ x, __hip_bfloat16* __restrict__ xb,
        const float* __restrict__ p0a, const float* __restrict__ p0b,
        const float* __restrict__ p1a, const float* __restrict__ p1b,
        const float* __restrict__ p2a, const float* __restrict__ p2b,
        const float* __restrict__ p3a, const float* __restrict__ p3b,
        const float* __restrict__ p4a, const float* __restrict__ p4b,
        const float* __restrict__ p5a, const float* __restrict__ p5b,
        __hip_bfloat16* __restrict__ wout) {
    int b = blockIdx.x, t = threadIdx.x;
    if (b < CAST_B) {
        int i = b * 256 + t;
        if (i < N_NODES * 32) {
            float4 v = ((const float4*)x)[i];
            float2 lo = {v.x, v.y}, hi = {v.z, v.w};
            ((__hip_bfloat162*)xb)[i * 2 + 0] = __float22bfloat162_rn(lo);
            ((__hip_bfloat162*)xb)[i * 2 + 1] = __float22bfloat162_rn(hi);
        }
        return;
    }
    int idx = (b - CAST_B) * 256 + t;
    if (idx >= 6 * 32768) return;
    int g = idx >> 15;
    int r = idx & 32767;
    int i = r & 7;
    int k = ((r >> 12) & 7) * 32 + ((r >> 7) & 3) * 8 + i;
    int c = ((r >> 9) & 7) * 16 + ((r >> 3) & 15);
    const float* a; const float* bb;
    switch (g) {
        case 0: a = p0a; bb = p0b; break;
        case 1: a = p1a; bb = p1b; break;
        case 2: a = p2a; bb = p2b; break;
        case 3: a = p3a; bb = p3b; break;
        case 4: a = p4a; bb = p4b; break;
        default: a = p5a; bb = p5b; break;
    }
    const float* srcp = (k < 128) ? a : bb;
    int kk2 = k & 127;
    wout[idx] = __float2bfloat16(srcp[kk2 * HD + c]);
}

// ---------------- mean aggregation (R8-proven: wave per node, 50000 waves) ----------------

__global__ __launch_bounds__(256) void agg_kernel(const __hip_bfloat16* __restrict__ X,
                                                  const int* __restrict__ row_ptr,
                                                  const int* __restrict__ col,
                                                  const float* __restrict__ degInv,
                                                  __hip_bfloat16* __restrict__ out) {
    int w = (blockIdx.x * blockDim.x + threadIdx.x) >> 6;
    int lane = threadIdx.x & 63;
    if (w >= N_NODES) return;
    int beg = row_ptr[w], end = row_ptr[w + 1];
    int g = lane >> 4;       // edge subgroup 0..3
    int p = lane & 15;       // dim octet
    float acc[8] = {};
    #pragma unroll 2
    for (int j = beg + g; j < end; j += 4) {
        int s = col[j];
        uint4 v = *(const uint4*)&X[(size_t)s * HD + p * 8];
        acc[0] += bf_lo(v.x); acc[1] += bf_hi(v.x);
        acc[2] += bf_lo(v.y); acc[3] += bf_hi(v.y);
        acc[4] += bf_lo(v.z); acc[5] += bf_hi(v.z);
        acc[6] += bf_lo(v.w); acc[7] += bf_hi(v.w);
    }
    #pragma unroll
    for (int k = 0; k < 8; ++k) {
        acc[k] += __shfl_xor(acc[k], 16, 64);
        acc[k] += __shfl_xor(acc[k], 32, 64);
    }
    if (g == 0) {
        float inv = degInv[w];
        uint ow[4];
        #pragma unroll
        for (int k = 0; k < 4; ++k) {
            float2 vv = {acc[2 * k] * inv, acc[2 * k + 1] * inv};
            union { __hip_bfloat162 h; uint u; } cv;
            cv.h = __float22bfloat162_rn(vv);
            ow[k] = cv.u;
        }
        *(uint4*)&out[(size_t)w * HD + p * 8] = make_uint4(ow[0], ow[1], ow[2], ow[3]);
    }
}

// ---------------- dual-matmul via MFMA: out = relu([A1|A2]@Bp + b) ----------------

__global__ __launch_bounds__(256) void gemm_mfma_kernel(
        const __hip_bfloat16* __restrict__ A1, const __hip_bfloat16* __restrict__ A2,
        const __hip_bfloat16* __restrict__ Bp, const float* __restrict__ bias,
        __hip_bfloat16* __restrict__ out) {
    int lane = threadIdx.x & 63;
    int wave = threadIdx.x >> 6;
    int row0 = blockIdx.x * 64 + wave * 16;
    int arow = row0 + (lane & 15);
    int arow_c = min(arow, N_NODES - 1);
    int kb = (lane >> 4) << 3;
    f32x4 acc[8] = {};
    const bf16x8* __restrict__ Bp8 = (const bf16x8*)Bp;
    #pragma unroll
    for (int kk = 0; kk < 8; ++kk) {
        const __hip_bfloat16* __restrict__ As = (kk < 4) ? A1 : A2;
        int k0 = (kk & 3) * 32 + kb;
        bf16x8 af = *(const bf16x8*)&As[(size_t)arow_c * HD + k0];
        #pragma unroll
        for (int n = 0; n < 8; ++n) {
            bf16x8 bf = Bp8[(kk * 8 + n) * 64 + lane];
            acc[n] = __builtin_amdgcn_mfma_f32_16x16x32_bf16(af, bf, acc[n], 0, 0, 0);
        }
    }
    int crow0 = row0 + ((lane >> 4) << 2);
    int ccol = lane & 15;
    #pragma unroll
    for (int n = 0; n < 8; ++n) {
        int c = n * 16 + ccol;
        float bv = bias[c];
        #pragma unroll
        for (int i = 0; i < 4; ++i) {
            int row = crow0 + i;
            if (row < N_NODES) {
                float v = acc[n][i] + bv;
                out[(size_t)row * HD + c] = __float2bfloat16(fmaxf(v, 0.f));
            }
        }
    }
}

// ---------------- fused h2-GEMM + JK linear + POOL (4 waves + block pooling) ----------------
// h2 = relu(A@Wl2 + H1@Wr2 + b2) staged per-wave in LDS;
// D = relu(H1@WlinLo + h2@WlinHi + bjk) -> out, and pooled by graph into p.
// Block covers 64 consecutive nodes; batch sorted => <=2 graphs per block (4 slots + fallback).

__global__ __launch_bounds__(256) void gemm2jk_kernel(
        const __hip_bfloat16* __restrict__ A, const __hip_bfloat16* __restrict__ H1,
        const __hip_bfloat16* __restrict__ BpS, const float* __restrict__ b2,
        const __hip_bfloat16* __restrict__ BpJ, const float* __restrict__ bjk,
        const int* __restrict__ batch, float* __restrict__ p,
        __hip_bfloat16* __restrict__ out) {
    __shared__ __hip_bfloat16 As[64][LDSP];
    __shared__ float pacc[4][HD];
    __shared__ int used[4];
    int lane = threadIdx.x & 63;
    int wave = threadIdx.x >> 6;
    int row0 = blockIdx.x * 64 + wave * 16;
    int arow_c = min(row0 + (lane & 15), N_NODES - 1);
    int lrow = wave * 16 + (lane & 15);
    int kb = (lane >> 4) << 3;
    const bf16x8* __restrict__ BpS8 = (const bf16x8*)BpS;
    const bf16x8* __restrict__ BpJ8 = (const bf16x8*)BpJ;

    for (int i = threadIdx.x; i < 4 * HD; i += 256) ((float*)pacc)[i] = 0.f;
    if (threadIdx.x < 4) used[threadIdx.x] = 0;
    __syncthreads();

    // phase B: h2 tile = relu(A@Wl2 + H1@Wr2 + b2)
    f32x4 acc[8] = {};
    #pragma unroll
    for (int kk = 0; kk < 8; ++kk) {
        const __hip_bfloat16* __restrict__ Asrc = (kk < 4) ? A : H1;
        int k0 = (kk & 3) * 32 + kb;
        bf16x8 af = *(const bf16x8*)&Asrc[(size_t)arow_c * HD + k0];
        #pragma unroll
        for (int n = 0; n < 8; ++n) {
            bf16x8 bf = BpS8[(kk * 8 + n) * 64 + lane];
            acc[n] = __builtin_amdgcn_mfma_f32_16x16x32_bf16(af, bf, acc[n], 0, 0, 0);
        }
    }
    // phase C: stash h2 into this wave's own LDS rows
    int crl0 = wave * 16 + ((lane >> 4) << 2);
    int ccol = lane & 15;
    #pragma unroll
    for (int n = 0; n < 8; ++n) {
        int c = n * 16 + ccol;
        float bv = b2[c];
        #pragma unroll
        for (int i = 0; i < 4; ++i) {
            float v = fmaxf(acc[n][i] + bv, 0.f);
            As[crl0 + i][c] = __float2bfloat16(v);
        }
    }
    // phase D: JK GEMM (k<128: H1 self from global; k>=128: h2 from LDS)
    f32x4 acc2[8] = {};
    #pragma unroll
    for (int kk = 0; kk < 8; ++kk) {
        int k0 = (kk & 3) * 32 + kb;
        bf16x8 af = (kk < 4) ? *(const bf16x8*)&H1[(size_t)arow_c * HD + k0]
                             : *(const bf16x8*)&As[lrow][k0];
        #pragma unroll
        for (int n = 0; n < 8; ++n) {
            bf16x8 bf = BpJ8[(kk * 8 + n) * 64 + lane];
            acc2[n] = __builtin_amdgcn_mfma_f32_16x16x32_bf16(af, bf, acc2[n], 0, 0, 0);
        }
    }
    // epilogue: write D + pool into LDS slots
    int gmin = batch[blockIdx.x * 64];
    int crow0 = row0 + ((lane >> 4) << 2);
    #pragma unroll
    for (int i = 0; i < 4; ++i) {
        int row = crow0 + i;
        if (row < N_NODES) {
            int rel = batch[row] - gmin;
            bool fits = (rel < 4);
            if (fits) used[rel] = 1;
            #pragma unroll
            for (int n = 0; n < 8; ++n) {
                int c = n * 16 + ccol;
                float v = fmaxf(acc2[n][i] + bjk[c], 0.f);
                out[(size_t)row * HD + c] = __float2bfloat16(v);
                if (fits) atomicAdd(&pacc[rel][c], v);
                else atomicAdd(&p[(size_t)batch[row] * HD + c], v);
            }
        }
    }
    __syncthreads();
    for (int i = threadIdx.x; i < 4 * HD; i += 256) {
        int slot = i >> 7;
        if (used[slot]) {
            float v = ((float*)pacc)[i];
            atomicAdd(&p[(size_t)(gmin + slot) * HD + (i & 127)], v);
        }
    }
}

// ---------------- head: BN + MLP + softmax ----------------

__global__ void head_kernel(const float* __restrict__ p0, const float* __restrict__ p1,
                            const float* __restrict__ gamma, const float* __restrict__ beta,
                            const float* __restrict__ rm, const float* __restrict__ rv,
                            const float* __restrict__ W1, const float* __restrict__ b1,
                            const float* __restrict__ W2, const float* __restrict__ b2,
                            float* __restrict__ out) {
    __shared__ float xb[256];
    __shared__ float hh[128];
    __shared__ float oo[10];
    int g = blockIdx.x, t = threadIdx.x;  // 128 threads
    {
        float v0 = p0[g * HD + t];
        float v1 = p1[g * HD + t];
        int d1 = t + 128;
        xb[t]  = (v0 - rm[t])  * rsqrtf(rv[t]  + 1e-5f) * gamma[t]  + beta[t];
        xb[d1] = (v1 - rm[d1]) * rsqrtf(rv[d1] + 1e-5f) * gamma[d1] + beta[d1];
    }
    __syncthreads();
    float acc = b1[t];
    for (int d = 0; d < 256; ++d) acc += xb[d] * W1[d * HD + t];
    hh[t] = fmaxf(acc, 0.f);
    __syncthreads();
    if (t < 10) {
        float o = b2[t];
        for (int d = 0; d < 128; ++d) o += hh[d] * W2[d * 10 + t];
        oo[t] = o;
    }
    __syncthreads();
    if (t < 10) {
        float m = oo[0];
        for (int c = 1; c < 10; ++c) m = fmaxf(m, oo[c]);
        float sum = 0.f;
        for (int c = 0; c < 10; ++c) sum += expf(oo[c] - m);
        out[g * 10 + t] = expf(oo[t] - m) / sum;
    }
}

// ---------------- launcher ----------------

extern "C" void kernel_launch(void* const* d_in, const int* in_sizes, int n_in,
                              void* d_out, int out_size, void* d_ws, size_t ws_size,
                              hipStream_t stream) {
    const float* x     = (const float*)d_in[0];
    const int*   ei    = (const int*)d_in[1];
    const int*   batch = (const int*)d_in[2];
    const int*   src = ei;
    const int*   dst = ei + N_EDGES;

    const float* b0_Wl1 = (const float*)d_in[4];
    const float* b0_Wr1 = (const float*)d_in[5];
    const float* b0_b1  = (const float*)d_in[6];
    const float* b0_Wl2 = (const float*)d_in[7];
    const float* b0_Wr2 = (const float*)d_in[8];
    const float* b0_b2  = (const float*)d_in[9];
    const float* b0_Wlin = (const float*)d_in[10];
    const float* b0_blin = (const float*)d_in[11];
    const float* b1_Wl1 = (const float*)d_in[12];
    const float* b1_Wr1 = (const float*)d_in[13];
    const float* b1_b1  = (const float*)d_in[14];
    const float* b1_Wl2 = (const float*)d_in[15];
    const float* b1_Wr2 = (const float*)d_in[16];
    const float* b1_b2  = (const float*)d_in[17];
    const float* b1_Wlin = (const float*)d_in[18];
    const float* b1_blin = (const float*)d_in[19];
    const float* bn_gamma = (const float*)d_in[20];
    const float* bn_beta  = (const float*)d_in[21];
    const float* bn_rm    = (const float*)d_in[22];
    const float* bn_rv    = (const float*)d_in[23];
    const float* lin1_W = (const float*)d_in[24];
    const float* lin1_b = (const float*)d_in[25];
    const float* lin2_W = (const float*)d_in[26];
    const float* lin2_b = (const float*)d_in[27];

    float* out = (float*)d_out;

    char* ws = (char*)d_ws;
    size_t off = 0;
    auto alloc = [&](size_t bytes) { void* p = ws + off; off += (bytes + 255) & ~size_t(255); return p; };
    int* histG      = (int*)alloc((size_t)NBA * NBUCKET * 4);
    int* offsG      = (int*)alloc((size_t)NBUCKET * OFFS_LD * 4);
    int* bucket_tot = (int*)alloc(NBUCKET * 4);
    int* bucket_base= (int*)alloc((NBUCKET + 1) * 4);
    uint* packed    = (uint*)alloc((size_t)N_EDGES * 4);
    int* col        = (int*)alloc((size_t)N_EDGES * 4);
    int* row_ptr    = (int*)alloc((N_NODES + 1) * 4);
    float* degInv   = (float*)alloc((size_t)N_NODES * 4);
    __hip_bfloat16* Xb = (__hip_bfloat16*)alloc((size_t)N_NODES * HD * 2);
    __hip_bfloat16* A  = (__hip_bfloat16*)alloc((size_t)N_NODES * HD * 2);
    __hip_bfloat16* B  = (__hip_bfloat16*)alloc((size_t)N_NODES * HD * 2);
    __hip_bfloat16* D  = (__hip_bfloat16*)alloc((size_t)N_NODES * HD * 2);
    __hip_bfloat16* Bpack = (__hip_bfloat16*)alloc(6 * 32768 * 2);
    float* p0 = (float*)alloc(NG * HD * 4);
    float* p1 = (float*)alloc(NG * HD * 4);
    (void)ws_size; (void)n_in; (void)in_sizes; (void)out_size;

    // ---- CSR build via bucket sort (no global atomics) ----
    bhist_kernel<<<NBA, 256, 0, stream>>>(dst, histG);
    scanb_kernel<<<NBUCKET, 256, 0, stream>>>(histG, offsG, bucket_tot);
    scanbase_kernel<<<1, 256, 0, stream>>>(bucket_tot, bucket_base);
    scatter_kernel<<<NBA, 256, 0, stream>>>(src, dst, bucket_base, offsG, packed);
    csr_bucket_kernel<<<NBUCKET, 256, 0, stream>>>(packed, bucket_base, row_ptr, degInv, col);

    prep_kernel<<<CAST_B + PACK_B, 256, 0, stream>>>(
        x, Xb,
        b0_Wl1, b0_Wr1, b0_Wl2, b0_Wr2, b0_Wlin, b0_Wlin + 128 * HD,
        b1_Wl1, b1_Wr1, b1_Wl2, b1_Wr2, b1_Wlin, b1_Wlin + 128 * HD, Bpack);
    hipMemsetAsync(p0, 0, 2 * NG * HD * 4, stream);  // p0,p1 contiguous

    const int AGG_B = (N_NODES * 64 + 255) / 256;
    const int GEMM_B = (N_NODES + 63) / 64;

    __hip_bfloat16* Bp0 = Bpack + 0 * 32768;
    __hip_bfloat16* Bp1 = Bpack + 1 * 32768;
    __hip_bfloat16* Bp2 = Bpack + 2 * 32768;
    __hip_bfloat16* Bp3 = Bpack + 3 * 32768;
    __hip_bfloat16* Bp4 = Bpack + 4 * 32768;
    __hip_bfloat16* Bp5 = Bpack + 5 * 32768;

    // block 0
    agg_kernel<<<AGG_B, 256, 0, stream>>>(Xb, row_ptr, col, degInv, A);
    gemm_mfma_kernel<<<GEMM_B, 256, 0, stream>>>(A, Xb, Bp0, b0_b1, B);            // h1
    agg_kernel<<<AGG_B, 256, 0, stream>>>(B, row_ptr, col, degInv, A);
    gemm2jk_kernel<<<GEMM_B, 256, 0, stream>>>(A, B, Bp1, b0_b2, Bp2, b0_blin,
                                               batch, p0, D);                      // h2+JK+pool
    // block 1
    agg_kernel<<<AGG_B, 256, 0, stream>>>(D, row_ptr, col, degInv, A);
    gemm_mfma_kernel<<<GEMM_B, 256, 0, stream>>>(A, D, Bp3, b1_b1, B);             // h1
    agg_kernel<<<AGG_B, 256, 0, stream>>>(B, row_ptr, col, degInv, A);
    gemm2jk_kernel<<<GEMM_B, 256, 0, stream>>>(A, B, Bp4, b1_b2, Bp5, b1_blin,
                                               batch, p1, D);                      // h2+JK+pool
    // head
    head_kernel<<<NG, HD, 0, stream>>>(p0, p1, bn_gamma, bn_beta, bn_rm, bn_rv,
                                       lin1_W, lin1_b, lin2_W, lin2_b, out);
}

// Round 12
// 498.237 us; speedup vs baseline: 1.2739x; 1.0934x over previous
//
#include <hip/hip_runtime.h>
#include <hip/hip_bf16.h>

#define N_NODES 50000
#define N_EDGES 1600000
#define NG      256
#define HD      128
#define NBUCKET 782          // dst >> 6 (64 nodes per bucket)
#define NPB     64           // nodes per bucket
#define EPB     4096         // edges per block in hist/scatter
#define NBA     391          // ceil(N_EDGES / EPB)
#define OFFS_LD 392          // leading dim of offsG
#define LDSP    136          // padded LDS row (bf16)
#define CAST_B  6250         // blocks of prep doing cast (50000*32/256)
#define PACK_B  768          // blocks of prep doing weight pack (6*32768/256)

typedef __attribute__((ext_vector_type(8))) __bf16 bf16x8;
typedef __attribute__((ext_vector_type(4))) float f32x4;
typedef unsigned int uint;

__device__ __forceinline__ float bf_lo(uint u) { return __uint_as_float(u << 16); }
__device__ __forceinline__ float bf_hi(uint u) { return __uint_as_float(u & 0xFFFF0000u); }

// ---------------- bucket histogram ----------------

__global__ __launch_bounds__(256) void bhist_kernel(const int* __restrict__ dst,
                                                    int* __restrict__ histG) {
    __shared__ int hist[NBUCKET];
    int b = blockIdx.x, t = threadIdx.x;
    for (int i = t; i < NBUCKET; i += 256) hist[i] = 0;
    __syncthreads();
    int e0 = b * EPB;
    #pragma unroll
    for (int i = 0; i < 16; ++i) {
        int e = e0 + i * 256 + t;
        if (e < N_EDGES) atomicAdd(&hist[dst[e] >> 6], 1);
    }
    __syncthreads();
    for (int i = t; i < NBUCKET; i += 256) histG[b * NBUCKET + i] = hist[i];
}

// ---------------- per-bucket scan over blocks: offsG[bucket][block], bucket_tot ----------------

__global__ __launch_bounds__(256) void scanb_kernel(const int* __restrict__ histG,
                                                    int* __restrict__ offsG,
                                                    int* __restrict__ bucket_tot) {
    __shared__ int sh[256];
    int bucket = blockIdx.x, t = threadIdx.x;
    int k0 = 2 * t, k1 = 2 * t + 1;
    int a0 = (k0 < NBA) ? histG[k0 * NBUCKET + bucket] : 0;
    int a1 = (k1 < NBA) ? histG[k1 * NBUCKET + bucket] : 0;
    int pair = a0 + a1;
    sh[t] = pair;
    __syncthreads();
    for (int off = 1; off < 256; off <<= 1) {
        int x = (t >= off) ? sh[t - off] : 0;
        __syncthreads();
        sh[t] += x;
        __syncthreads();
    }
    int excl = sh[t] - pair;
    if (k0 < NBA) offsG[bucket * OFFS_LD + k0] = excl;
    if (k1 < NBA) offsG[bucket * OFFS_LD + k1] = excl + a0;
    if (t == 255) bucket_tot[bucket] = sh[255];
}

// ---------------- scan bucket totals (1024-wide: 256 thr x 4) ----------------

__global__ __launch_bounds__(256) void scanbase_kernel(const int* __restrict__ tot,
                                                       int* __restrict__ base) {
    __shared__ int sh[256];
    int t = threadIdx.x;
    int b0 = t * 4;
    int v0 = (b0 + 0 < NBUCKET) ? tot[b0 + 0] : 0;
    int v1 = (b0 + 1 < NBUCKET) ? tot[b0 + 1] : 0;
    int v2 = (b0 + 2 < NBUCKET) ? tot[b0 + 2] : 0;
    int v3 = (b0 + 3 < NBUCKET) ? tot[b0 + 3] : 0;
    int s3 = v0 + v1 + v2 + v3;
    sh[t] = s3;
    __syncthreads();
    for (int off = 1; off < 256; off <<= 1) {
        int x = (t >= off) ? sh[t - off] : 0;
        __syncthreads();
        sh[t] += x;
        __syncthreads();
    }
    int run = sh[t] - s3;
    if (b0 + 0 < NBUCKET) base[b0 + 0] = run;
    run += v0;
    if (b0 + 1 < NBUCKET) base[b0 + 1] = run;
    run += v1;
    if (b0 + 2 < NBUCKET) base[b0 + 2] = run;
    run += v2;
    if (b0 + 3 < NBUCKET) base[b0 + 3] = run;
    if (t == 255) base[NBUCKET] = sh[255];
}

// ---------------- scatter into bucket-grouped packed array ----------------
// packed[e] = (dst&63)<<16 | src   (src < 65536)

__global__ __launch_bounds__(256) void scatter_kernel(const int* __restrict__ src,
                                                      const int* __restrict__ dst,
                                                      const int* __restrict__ base,
                                                      const int* __restrict__ offsG,
                                                      uint* __restrict__ packed) {
    __shared__ int cur[NBUCKET];
    int b = blockIdx.x, t = threadIdx.x;
    for (int i = t; i < NBUCKET; i += 256) cur[i] = base[i] + offsG[i * OFFS_LD + b];
    __syncthreads();
    int e0 = b * EPB;
    #pragma unroll
    for (int i = 0; i < 16; ++i) {
        int e = e0 + i * 256 + t;
        if (e < N_EDGES) {
            int d = dst[e];
            int s = src[e];
            int pos = atomicAdd(&cur[d >> 6], 1);
            packed[pos] = ((uint)(d & 63) << 16) | (uint)s;
        }
    }
}

// ---------------- per-bucket CSR finalize (782 blocks, 64 nodes each) ----------------

__global__ __launch_bounds__(256) void csr_bucket_kernel(const uint* __restrict__ packed,
                                                         const int* __restrict__ base,
                                                         int* __restrict__ row_ptr,
                                                         float* __restrict__ degInv,
                                                         int* __restrict__ col) {
    __shared__ int cnt[NPB];
    __shared__ int sh[NPB];
    __shared__ int cur[NPB];
    int bucket = blockIdx.x, t = threadIdx.x;
    if (t < NPB) cnt[t] = 0;
    __syncthreads();
    int s = base[bucket], e = base[bucket + 1];
    for (int j = s + t; j < e; j += 256) atomicAdd(&cnt[packed[j] >> 16], 1);
    __syncthreads();
    int v = 0;
    if (t < NPB) { v = cnt[t]; sh[t] = v; }
    __syncthreads();
    for (int off = 1; off < NPB; off <<= 1) {
        int x = 0;
        if (t < NPB && t >= off) x = sh[t - off];
        __syncthreads();
        if (t < NPB) sh[t] += x;
        __syncthreads();
    }
    if (t < NPB) {
        int excl = sh[t] - v;
        int id = bucket * NPB + t;
        if (id < N_NODES) {
            row_ptr[id] = s + excl;
            degInv[id] = 1.0f / fmaxf((float)v, 1.0f);
            if (id == N_NODES - 1) row_ptr[N_NODES] = e;
        }
        cur[t] = s + excl;
    }
    __syncthreads();
    for (int j = s + t; j < e; j += 256) {
        uint pk = packed[j];
        int dl = (int)(pk >> 16);
        int pos = atomicAdd(&cur[dl], 1);
        col[pos] = (int)(pk & 0xFFFFu);
    }
}

// ---------------- prep: x cast (blocks < CAST_B) + weight pack (rest) ----------------
// pack layout: k = kk*32 + (lane>>4)*8 + i, col = n*16 + (lane&15).

__global__ __launch_bounds__(256) void prep_kernel(
        const float* __restrict__ x, __hip_bfloat16* __restrict__ xb,
        const float* __restrict__ p0a, const float* __restrict__ p0b,
        const float* __restrict__ p1a, const float* __restrict__ p1b,
        const float* __restrict__ p2a, const float* __restrict__ p2b,
        const float* __restrict__ p3a, const float* __restrict__ p3b,
        const float* __restrict__ p4a, const float* __restrict__ p4b,
        const float* __restrict__ p5a, const float* __restrict__ p5b,
        __hip_bfloat16* __restrict__ wout) {
    int b = blockIdx.x, t = threadIdx.x;
    if (b < CAST_B) {
        int i = b * 256 + t;
        if (i < N_NODES * 32) {
            float4 v = ((const float4*)x)[i];
            float2 lo = {v.x, v.y}, hi = {v.z, v.w};
            ((__hip_bfloat162*)xb)[i * 2 + 0] = __float22bfloat162_rn(lo);
            ((__hip_bfloat162*)xb)[i * 2 + 1] = __float22bfloat162_rn(hi);
        }
        return;
    }
    int idx = (b - CAST_B) * 256 + t;
    if (idx >= 6 * 32768) return;
    int g = idx >> 15;
    int r = idx & 32767;
    int i = r & 7;
    int k = ((r >> 12) & 7) * 32 + ((r >> 7) & 3) * 8 + i;
    int c = ((r >> 9) & 7) * 16 + ((r >> 3) & 15);
    const float* a; const float* bb;
    switch (g) {
        case 0: a = p0a; bb = p0b; break;
        case 1: a = p1a; bb = p1b; break;
        case 2: a = p2a; bb = p2b; break;
        case 3: a = p3a; bb = p3b; break;
        case 4: a = p4a; bb = p4b; break;
        default: a = p5a; bb = p5b; break;
    }
    const float* srcp = (k < 128) ? a : bb;
    int kk2 = k & 127;
    wout[idx] = __float2bfloat16(srcp[kk2 * HD + c]);
}

// ---------------- mean aggregation (R8-proven: wave per node, 50000 waves) ----------------

__global__ __launch_bounds__(256) void agg_kernel(const __hip_bfloat16* __restrict__ X,
                                                  const int* __restrict__ row_ptr,
                                                  const int* __restrict__ col,
                                                  const float* __restrict__ degInv,
                                                  __hip_bfloat16* __restrict__ out) {
    int w = (blockIdx.x * blockDim.x + threadIdx.x) >> 6;
    int lane = threadIdx.x & 63;
    if (w >= N_NODES) return;
    int beg = row_ptr[w], end = row_ptr[w + 1];
    int g = lane >> 4;       // edge subgroup 0..3
    int p = lane & 15;       // dim octet
    float acc[8] = {};
    #pragma unroll 2
    for (int j = beg + g; j < end; j += 4) {
        int s = col[j];
        uint4 v = *(const uint4*)&X[(size_t)s * HD + p * 8];
        acc[0] += bf_lo(v.x); acc[1] += bf_hi(v.x);
        acc[2] += bf_lo(v.y); acc[3] += bf_hi(v.y);
        acc[4] += bf_lo(v.z); acc[5] += bf_hi(v.z);
        acc[6] += bf_lo(v.w); acc[7] += bf_hi(v.w);
    }
    #pragma unroll
    for (int k = 0; k < 8; ++k) {
        acc[k] += __shfl_xor(acc[k], 16, 64);
        acc[k] += __shfl_xor(acc[k], 32, 64);
    }
    if (g == 0) {
        float inv = degInv[w];
        uint ow[4];
        #pragma unroll
        for (int k = 0; k < 4; ++k) {
            float2 vv = {acc[2 * k] * inv, acc[2 * k + 1] * inv};
            union { __hip_bfloat162 h; uint u; } cv;
            cv.h = __float22bfloat162_rn(vv);
            ow[k] = cv.u;
        }
        *(uint4*)&out[(size_t)w * HD + p * 8] = make_uint4(ow[0], ow[1], ow[2], ow[3]);
    }
}

// ---------------- dual-matmul via MFMA: out = relu([A1|A2]@Bp + b) ----------------

__global__ __launch_bounds__(256) void gemm_mfma_kernel(
        const __hip_bfloat16* __restrict__ A1, const __hip_bfloat16* __restrict__ A2,
        const __hip_bfloat16* __restrict__ Bp, const float* __restrict__ bias,
        __hip_bfloat16* __restrict__ out) {
    int lane = threadIdx.x & 63;
    int wave = threadIdx.x >> 6;
    int row0 = blockIdx.x * 64 + wave * 16;
    int arow = row0 + (lane & 15);
    int arow_c = min(arow, N_NODES - 1);
    int kb = (lane >> 4) << 3;
    f32x4 acc[8] = {};
    const bf16x8* __restrict__ Bp8 = (const bf16x8*)Bp;
    #pragma unroll
    for (int kk = 0; kk < 8; ++kk) {
        const __hip_bfloat16* __restrict__ As = (kk < 4) ? A1 : A2;
        int k0 = (kk & 3) * 32 + kb;
        bf16x8 af = *(const bf16x8*)&As[(size_t)arow_c * HD + k0];
        #pragma unroll
        for (int n = 0; n < 8; ++n) {
            bf16x8 bf = Bp8[(kk * 8 + n) * 64 + lane];
            acc[n] = __builtin_amdgcn_mfma_f32_16x16x32_bf16(af, bf, acc[n], 0, 0, 0);
        }
    }
    int crow0 = row0 + ((lane >> 4) << 2);
    int ccol = lane & 15;
    #pragma unroll
    for (int n = 0; n < 8; ++n) {
        int c = n * 16 + ccol;
        float bv = bias[c];
        #pragma unroll
        for (int i = 0; i < 4; ++i) {
            int row = crow0 + i;
            if (row < N_NODES) {
                float v = acc[n][i] + bv;
                out[(size_t)row * HD + c] = __float2bfloat16(fmaxf(v, 0.f));
            }
        }
    }
}

// ---------------- fused h2-GEMM + JK linear (R8-proven: 4 self-contained waves) ----------------

__global__ __launch_bounds__(256) void gemm2jk_kernel(
        const __hip_bfloat16* __restrict__ A, const __hip_bfloat16* __restrict__ H1,
        const __hip_bfloat16* __restrict__ BpS, const float* __restrict__ b2,
        const __hip_bfloat16* __restrict__ BpJ, const float* __restrict__ bjk,
        __hip_bfloat16* __restrict__ out) {
    __shared__ __hip_bfloat16 As[64][LDSP];
    int lane = threadIdx.x & 63;
    int wave = threadIdx.x >> 6;
    int row0 = blockIdx.x * 64 + wave * 16;
    int arow_c = min(row0 + (lane & 15), N_NODES - 1);
    int lrow = wave * 16 + (lane & 15);
    int kb = (lane >> 4) << 3;
    const bf16x8* __restrict__ BpS8 = (const bf16x8*)BpS;
    const bf16x8* __restrict__ BpJ8 = (const bf16x8*)BpJ;

    // phase B: h2 tile = relu(A@Wl2 + H1@Wr2 + b2)
    f32x4 acc[8] = {};
    #pragma unroll
    for (int kk = 0; kk < 8; ++kk) {
        const __hip_bfloat16* __restrict__ Asrc = (kk < 4) ? A : H1;
        int k0 = (kk & 3) * 32 + kb;
        bf16x8 af = *(const bf16x8*)&Asrc[(size_t)arow_c * HD + k0];
        #pragma unroll
        for (int n = 0; n < 8; ++n) {
            bf16x8 bf = BpS8[(kk * 8 + n) * 64 + lane];
            acc[n] = __builtin_amdgcn_mfma_f32_16x16x32_bf16(af, bf, acc[n], 0, 0, 0);
        }
    }
    // phase C: stash h2 into this wave's own LDS rows
    int crl0 = wave * 16 + ((lane >> 4) << 2);
    int ccol = lane & 15;
    #pragma unroll
    for (int n = 0; n < 8; ++n) {
        int c = n * 16 + ccol;
        float bv = b2[c];
        #pragma unroll
        for (int i = 0; i < 4; ++i) {
            float v = fmaxf(acc[n][i] + bv, 0.f);
            As[crl0 + i][c] = __float2bfloat16(v);
        }
    }
    // phase D: JK GEMM (k<128: H1 self from global; k>=128: h2 from LDS)
    f32x4 acc2[8] = {};
    #pragma unroll
    for (int kk = 0; kk < 8; ++kk) {
        int k0 = (kk & 3) * 32 + kb;
        bf16x8 af = (kk < 4) ? *(const bf16x8*)&H1[(size_t)arow_c * HD + k0]
                             : *(const bf16x8*)&As[lrow][k0];
        #pragma unroll
        for (int n = 0; n < 8; ++n) {
            bf16x8 bf = BpJ8[(kk * 8 + n) * 64 + lane];
            acc2[n] = __builtin_amdgcn_mfma_f32_16x16x32_bf16(af, bf, acc2[n], 0, 0, 0);
        }
    }
    int crow0 = row0 + ((lane >> 4) << 2);
    #pragma unroll
    for (int n = 0; n < 8; ++n) {
        int c = n * 16 + ccol;
        float bv = bjk[c];
        #pragma unroll
        for (int i = 0; i < 4; ++i) {
            int row = crow0 + i;
            if (row < N_NODES) {
                float v = acc2[n][i] + bv;
                out[(size_t)row * HD + c] = __float2bfloat16(fmaxf(v, 0.f));
            }
        }
    }
}

// ---------------- pooling: node-chunk blocks + run-merged atomics (R8-proven) ----------------

__global__ __launch_bounds__(128) void pool_kernel(const __hip_bfloat16* __restrict__ h,
                                                   const int* __restrict__ batch,
                                                   float* __restrict__ p) {
    __shared__ int bsh[32];
    int n0 = blockIdx.x * 32, t = threadIdx.x;
    if (t < 32) bsh[t] = (n0 + t < N_NODES) ? batch[n0 + t] : -1;
    __syncthreads();
    float run = 0.f;
    int gprev = bsh[0];
    for (int r = 0; r < 32; ++r) {
        int n = n0 + r;
        if (n >= N_NODES) break;
        int g = bsh[r];
        float v = __bfloat162float(h[(size_t)n * HD + t]);
        if (g != gprev) {
            atomicAdd(&p[gprev * HD + t], run);
            run = 0.f;
            gprev = g;
        }
        run += v;
    }
    if (gprev >= 0) atomicAdd(&p[gprev * HD + t], run);
}

// ---------------- head: BN + MLP + softmax ----------------

__global__ void head_kernel(const float* __restrict__ p0, const float* __restrict__ p1,
                            const float* __restrict__ gamma, const float* __restrict__ beta,
                            const float* __restrict__ rm, const float* __restrict__ rv,
                            const float* __restrict__ W1, const float* __restrict__ b1,
                            const float* __restrict__ W2, const float* __restrict__ b2,
                            float* __restrict__ out) {
    __shared__ float xb[256];
    __shared__ float hh[128];
    __shared__ float oo[10];
    int g = blockIdx.x, t = threadIdx.x;  // 128 threads
    {
        float v0 = p0[g * HD + t];
        float v1 = p1[g * HD + t];
        int d1 = t + 128;
        xb[t]  = (v0 - rm[t])  * rsqrtf(rv[t]  + 1e-5f) * gamma[t]  + beta[t];
        xb[d1] = (v1 - rm[d1]) * rsqrtf(rv[d1] + 1e-5f) * gamma[d1] + beta[d1];
    }
    __syncthreads();
    float acc = b1[t];
    for (int d = 0; d < 256; ++d) acc += xb[d] * W1[d * HD + t];
    hh[t] = fmaxf(acc, 0.f);
    __syncthreads();
    if (t < 10) {
        float o = b2[t];
        for (int d = 0; d < 128; ++d) o += hh[d] * W2[d * 10 + t];
        oo[t] = o;
    }
    __syncthreads();
    if (t < 10) {
        float m = oo[0];
        for (int c = 1; c < 10; ++c) m = fmaxf(m, oo[c]);
        float sum = 0.f;
        for (int c = 0; c < 10; ++c) sum += expf(oo[c] - m);
        out[g * 10 + t] = expf(oo[t] - m) / sum;
    }
}

// ---------------- launcher ----------------

extern "C" void kernel_launch(void* const* d_in, const int* in_sizes, int n_in,
                              void* d_out, int out_size, void* d_ws, size_t ws_size,
                              hipStream_t stream) {
    const float* x     = (const float*)d_in[0];
    const int*   ei    = (const int*)d_in[1];
    const int*   batch = (const int*)d_in[2];
    const int*   src = ei;
    const int*   dst = ei + N_EDGES;

    const float* b0_Wl1 = (const float*)d_in[4];
    const float* b0_Wr1 = (const float*)d_in[5];
    const float* b0_b1  = (const float*)d_in[6];
    const float* b0_Wl2 = (const float*)d_in[7];
    const float* b0_Wr2 = (const float*)d_in[8];
    const float* b0_b2  = (const float*)d_in[9];
    const float* b0_Wlin = (const float*)d_in[10];
    const float* b0_blin = (const float*)d_in[11];
    const float* b1_Wl1 = (const float*)d_in[12];
    const float* b1_Wr1 = (const float*)d_in[13];
    const float* b1_b1  = (const float*)d_in[14];
    const float* b1_Wl2 = (const float*)d_in[15];
    const float* b1_Wr2 = (const float*)d_in[16];
    const float* b1_b2  = (const float*)d_in[17];
    const float* b1_Wlin = (const float*)d_in[18];
    const float* b1_blin = (const float*)d_in[19];
    const float* bn_gamma = (const float*)d_in[20];
    const float* bn_beta  = (const float*)d_in[21];
    const float* bn_rm    = (const float*)d_in[22];
    const float* bn_rv    = (const float*)d_in[23];
    const float* lin1_W = (const float*)d_in[24];
    const float* lin1_b = (const float*)d_in[25];
    const float* lin2_W = (const float*)d_in[26];
    const float* lin2_b = (const float*)d_in[27];

    float* out = (float*)d_out;

    char* ws = (char*)d_ws;
    size_t off = 0;
    auto alloc = [&](size_t bytes) { void* p = ws + off; off += (bytes + 255) & ~size_t(255); return p; };
    int* histG      = (int*)alloc((size_t)NBA * NBUCKET * 4);
    int* offsG      = (int*)alloc((size_t)NBUCKET * OFFS_LD * 4);
    int* bucket_tot = (int*)alloc(NBUCKET * 4);
    int* bucket_base= (int*)alloc((NBUCKET + 1) * 4);
    uint* packed    = (uint*)alloc((size_t)N_EDGES * 4);
    int* col        = (int*)alloc((size_t)N_EDGES * 4);
    int* row_ptr    = (int*)alloc((N_NODES + 1) * 4);
    float* degInv   = (float*)alloc((size_t)N_NODES * 4);
    __hip_bfloat16* Xb = (__hip_bfloat16*)alloc((size_t)N_NODES * HD * 2);
    __hip_bfloat16* A  = (__hip_bfloat16*)alloc((size_t)N_NODES * HD * 2);
    __hip_bfloat16* B  = (__hip_bfloat16*)alloc((size_t)N_NODES * HD * 2);
    __hip_bfloat16* D  = (__hip_bfloat16*)alloc((size_t)N_NODES * HD * 2);
    __hip_bfloat16* Bpack = (__hip_bfloat16*)alloc(6 * 32768 * 2);
    float* p0 = (float*)alloc(NG * HD * 4);
    float* p1 = (float*)alloc(NG * HD * 4);
    (void)ws_size; (void)n_in; (void)in_sizes; (void)out_size;

    // ---- CSR build via bucket sort (no global atomics) ----
    bhist_kernel<<<NBA, 256, 0, stream>>>(dst, histG);
    scanb_kernel<<<NBUCKET, 256, 0, stream>>>(histG, offsG, bucket_tot);
    scanbase_kernel<<<1, 256, 0, stream>>>(bucket_tot, bucket_base);
    scatter_kernel<<<NBA, 256, 0, stream>>>(src, dst, bucket_base, offsG, packed);
    csr_bucket_kernel<<<NBUCKET, 256, 0, stream>>>(packed, bucket_base, row_ptr, degInv, col);

    prep_kernel<<<CAST_B + PACK_B, 256, 0, stream>>>(
        x, Xb,
        b0_Wl1, b0_Wr1, b0_Wl2, b0_Wr2, b0_Wlin, b0_Wlin + 128 * HD,
        b1_Wl1, b1_Wr1, b1_Wl2, b1_Wr2, b1_Wlin, b1_Wlin + 128 * HD, Bpack);
    hipMemsetAsync(p0, 0, 2 * NG * HD * 4, stream);  // p0,p1 contiguous

    const int AGG_B = (N_NODES * 64 + 255) / 256;
    const int GEMM_B = (N_NODES + 63) / 64;
    const int POOL_B = (N_NODES + 31) / 32;

    __hip_bfloat16* Bp0 = Bpack + 0 * 32768;
    __hip_bfloat16* Bp1 = Bpack + 1 * 32768;
    __hip_bfloat16* Bp2 = Bpack + 2 * 32768;
    __hip_bfloat16* Bp3 = Bpack + 3 * 32768;
    __hip_bfloat16* Bp4 = Bpack + 4 * 32768;
    __hip_bfloat16* Bp5 = Bpack + 5 * 32768;

    // block 0
    agg_kernel<<<AGG_B, 256, 0, stream>>>(Xb, row_ptr, col, degInv, A);
    gemm_mfma_kernel<<<GEMM_B, 256, 0, stream>>>(A, Xb, Bp0, b0_b1, B);            // h1
    agg_kernel<<<AGG_B, 256, 0, stream>>>(B, row_ptr, col, degInv, A);
    gemm2jk_kernel<<<GEMM_B, 256, 0, stream>>>(A, B, Bp1, b0_b2, Bp2, b0_blin, D); // h2+JK
    pool_kernel<<<POOL_B, 128, 0, stream>>>(D, batch, p0);
    // block 1
    agg_kernel<<<AGG_B, 256, 0, stream>>>(D, row_ptr, col, degInv, A);
    gemm_mfma_kernel<<<GEMM_B, 256, 0, stream>>>(A, D, Bp3, b1_b1, B);             // h1
    agg_kernel<<<AGG_B, 256, 0, stream>>>(B, row_ptr, col, degInv, A);
    gemm2jk_kernel<<<GEMM_B, 256, 0, stream>>>(A, B, Bp4, b1_b2, Bp5, b1_blin, D); // h2+JK
    pool_kernel<<<POOL_B, 128, 0, stream>>>(D, batch, p1);
    // head
    head_kernel<<<NG, HD, 0, stream>>>(p0, p1, bn_gamma, bn_beta, bn_rm, bn_rv,
                                       lin1_W, lin1_b, lin2_W, lin2_b, out);
}

// Round 13
// 487.248 us; speedup vs baseline: 1.3026x; 1.0226x over previous
//
#include <hip/hip_runtime.h>
#include <hip/hip_bf16.h>

#define N_NODES 50000
#define N_EDGES 1600000
#define NG      256
#define HD      128
#define NBUCKET 782          // dst >> 6 (64 nodes per bucket)
#define NPB     64           // nodes per bucket
#define EPB     4096         // edges per block in hist/scatter
#define NBA     391          // ceil(N_EDGES / EPB)
#define OFFS_LD 392          // leading dim of offsG
#define LDSP    136          // padded LDS row (bf16)
#define PRE_HIST 391
#define PRE_CAST 6250        // 50000*32/256 float4s
#define PRE_PACK 768         // 6*32768/256
#define PRE_ZERO 64          // 64*256*4 = 65536 floats = p0+p1
#define AGG_BLKS 12500       // wave-per-node agg blocks
#define POOL_BLKS 1563       // ceil(50000/32)

typedef __attribute__((ext_vector_type(8))) __bf16 bf16x8;
typedef __attribute__((ext_vector_type(4))) float f32x4;
typedef unsigned int uint;

__device__ __forceinline__ float bf_lo(uint u) { return __uint_as_float(u << 16); }
__device__ __forceinline__ float bf_hi(uint u) { return __uint_as_float(u & 0xFFFF0000u); }

// ---------------- fused pre: bucket hist + x cast + weight pack + p zero ----------------

__global__ __launch_bounds__(256) void fused_pre_kernel(
        const int* __restrict__ dst, int* __restrict__ histG,
        const float* __restrict__ x, __hip_bfloat16* __restrict__ xb,
        const float* __restrict__ p0a, const float* __restrict__ p0b,
        const float* __restrict__ p1a, const float* __restrict__ p1b,
        const float* __restrict__ p2a, const float* __restrict__ p2b,
        const float* __restrict__ p3a, const float* __restrict__ p3b,
        const float* __restrict__ p4a, const float* __restrict__ p4b,
        const float* __restrict__ p5a, const float* __restrict__ p5b,
        __hip_bfloat16* __restrict__ wout, float* __restrict__ pzero) {
    __shared__ int hist[NBUCKET];
    int b = blockIdx.x, t = threadIdx.x;
    if (b < PRE_HIST) {
        for (int i = t; i < NBUCKET; i += 256) hist[i] = 0;
        __syncthreads();
        int e0 = b * EPB;
        #pragma unroll
        for (int i = 0; i < 16; ++i) {
            int e = e0 + i * 256 + t;
            if (e < N_EDGES) atomicAdd(&hist[dst[e] >> 6], 1);
        }
        __syncthreads();
        for (int i = t; i < NBUCKET; i += 256) histG[b * NBUCKET + i] = hist[i];
        return;
    }
    int b2 = b - PRE_HIST;
    if (b2 < PRE_CAST) {
        int i = b2 * 256 + t;
        if (i < N_NODES * 32) {
            float4 v = ((const float4*)x)[i];
            float2 lo = {v.x, v.y}, hi = {v.z, v.w};
            ((__hip_bfloat162*)xb)[i * 2 + 0] = __float22bfloat162_rn(lo);
            ((__hip_bfloat162*)xb)[i * 2 + 1] = __float22bfloat162_rn(hi);
        }
        return;
    }
    int b3 = b2 - PRE_CAST;
    if (b3 < PRE_PACK) {
        int idx = b3 * 256 + t;
        if (idx >= 6 * 32768) return;
        int g = idx >> 15;
        int r = idx & 32767;
        int i = r & 7;
        int k = ((r >> 12) & 7) * 32 + ((r >> 7) & 3) * 8 + i;
        int c = ((r >> 9) & 7) * 16 + ((r >> 3) & 15);
        const float* a; const float* bb;
        switch (g) {
            case 0: a = p0a; bb = p0b; break;
            case 1: a = p1a; bb = p1b; break;
            case 2: a = p2a; bb = p2b; break;
            case 3: a = p3a; bb = p3b; break;
            case 4: a = p4a; bb = p4b; break;
            default: a = p5a; bb = p5b; break;
        }
        const float* srcp = (k < 128) ? a : bb;
        int kk2 = k & 127;
        wout[idx] = __float2bfloat16(srcp[kk2 * HD + c]);
        return;
    }
    int b4 = b3 - PRE_PACK;
    int zi = (b4 * 256 + t) * 4;
    if (zi < 2 * NG * HD) {
        float4 z = {0.f, 0.f, 0.f, 0.f};
        *(float4*)&pzero[zi] = z;
    }
}

// ---------------- per-bucket scan over blocks: offsG[bucket][block], bucket_tot ----------------

__global__ __launch_bounds__(256) void scanb_kernel(const int* __restrict__ histG,
                                                    int* __restrict__ offsG,
                                                    int* __restrict__ bucket_tot) {
    __shared__ int sh[256];
    int bucket = blockIdx.x, t = threadIdx.x;
    int k0 = 2 * t, k1 = 2 * t + 1;
    int a0 = (k0 < NBA) ? histG[k0 * NBUCKET + bucket] : 0;
    int a1 = (k1 < NBA) ? histG[k1 * NBUCKET + bucket] : 0;
    int pair = a0 + a1;
    sh[t] = pair;
    __syncthreads();
    for (int off = 1; off < 256; off <<= 1) {
        int x = (t >= off) ? sh[t - off] : 0;
        __syncthreads();
        sh[t] += x;
        __syncthreads();
    }
    int excl = sh[t] - pair;
    if (k0 < NBA) offsG[bucket * OFFS_LD + k0] = excl;
    if (k1 < NBA) offsG[bucket * OFFS_LD + k1] = excl + a0;
    if (t == 255) bucket_tot[bucket] = sh[255];
}

// ---------------- local bucket-base scan helper (782 entries, 256 threads) ----------------
// Computes exclusive prefix of tot[] into baseL[]. Requires __syncthreads after.

__device__ __forceinline__ void local_base_scan(const int* __restrict__ tot,
                                                int* baseL, int* part) {
    int t = threadIdx.x;
    int b0 = t * 4;
    int v0 = (b0 + 0 < NBUCKET) ? tot[b0 + 0] : 0;
    int v1 = (b0 + 1 < NBUCKET) ? tot[b0 + 1] : 0;
    int v2 = (b0 + 2 < NBUCKET) ? tot[b0 + 2] : 0;
    int v3 = (b0 + 3 < NBUCKET) ? tot[b0 + 3] : 0;
    int s3 = v0 + v1 + v2 + v3;
    part[t] = s3;
    __syncthreads();
    for (int off = 1; off < 256; off <<= 1) {
        int x = (t >= off) ? part[t - off] : 0;
        __syncthreads();
        part[t] += x;
        __syncthreads();
    }
    int run = part[t] - s3;
    if (b0 + 0 < NBUCKET) baseL[b0 + 0] = run;
    run += v0;
    if (b0 + 1 < NBUCKET) baseL[b0 + 1] = run;
    run += v1;
    if (b0 + 2 < NBUCKET) baseL[b0 + 2] = run;
    run += v2;
    if (b0 + 3 < NBUCKET) baseL[b0 + 3] = run;
}

// ---------------- scatter into bucket-grouped packed array (local base scan) ----------------
// packed[e] = (dst&63)<<16 | src   (src < 65536)

__global__ __launch_bounds__(256) void scatter_kernel(const int* __restrict__ src,
                                                      const int* __restrict__ dst,
                                                      const int* __restrict__ tot,
                                                      const int* __restrict__ offsG,
                                                      uint* __restrict__ packed) {
    __shared__ int part[256];
    __shared__ int baseL[NBUCKET];
    __shared__ int cur[NBUCKET];
    int b = blockIdx.x, t = threadIdx.x;
    local_base_scan(tot, baseL, part);
    __syncthreads();
    for (int i = t; i < NBUCKET; i += 256) cur[i] = baseL[i] + offsG[i * OFFS_LD + b];
    __syncthreads();
    int e0 = b * EPB;
    #pragma unroll
    for (int i = 0; i < 16; ++i) {
        int e = e0 + i * 256 + t;
        if (e < N_EDGES) {
            int d = dst[e];
            int s = src[e];
            int pos = atomicAdd(&cur[d >> 6], 1);
            packed[pos] = ((uint)(d & 63) << 16) | (uint)s;
        }
    }
}

// ---------------- per-bucket CSR finalize (local base scan) ----------------

__global__ __launch_bounds__(256) void csr_bucket_kernel(const uint* __restrict__ packed,
                                                         const int* __restrict__ tot,
                                                         int* __restrict__ row_ptr,
                                                         float* __restrict__ degInv,
                                                         int* __restrict__ col) {
    __shared__ int part[256];
    __shared__ int baseL[NBUCKET];
    __shared__ int cnt[NPB];
    __shared__ int sh[NPB];
    __shared__ int cur[NPB];
    int bucket = blockIdx.x, t = threadIdx.x;
    local_base_scan(tot, baseL, part);
    if (t < NPB) cnt[t] = 0;
    __syncthreads();
    int s = baseL[bucket];
    int e = (bucket + 1 < NBUCKET) ? baseL[bucket + 1] : N_EDGES;
    for (int j = s + t; j < e; j += 256) atomicAdd(&cnt[packed[j] >> 16], 1);
    __syncthreads();
    int v = 0;
    if (t < NPB) { v = cnt[t]; sh[t] = v; }
    __syncthreads();
    for (int off = 1; off < NPB; off <<= 1) {
        int x = 0;
        if (t < NPB && t >= off) x = sh[t - off];
        __syncthreads();
        if (t < NPB) sh[t] += x;
        __syncthreads();
    }
    if (t < NPB) {
        int excl = sh[t] - v;
        int id = bucket * NPB + t;
        if (id < N_NODES) {
            row_ptr[id] = s + excl;
            degInv[id] = 1.0f / fmaxf((float)v, 1.0f);
            if (id == N_NODES - 1) row_ptr[N_NODES] = N_EDGES;
        }
        cur[t] = s + excl;
    }
    __syncthreads();
    for (int j = s + t; j < e; j += 256) {
        uint pk = packed[j];
        int dl = (int)(pk >> 16);
        int pos = atomicAdd(&cur[dl], 1);
        col[pos] = (int)(pk & 0xFFFFu);
    }
}

// ---------------- agg body (R8-proven wave-per-node) ----------------

__device__ __forceinline__ void agg_body(const __hip_bfloat16* __restrict__ X,
                                         const int* __restrict__ row_ptr,
                                         const int* __restrict__ col,
                                         const float* __restrict__ degInv,
                                         __hip_bfloat16* __restrict__ out,
                                         int blk) {
    int w = (blk * 256 + (int)threadIdx.x) >> 6;
    int lane = threadIdx.x & 63;
    if (w >= N_NODES) return;
    int beg = row_ptr[w], end = row_ptr[w + 1];
    int g = lane >> 4;       // edge subgroup 0..3
    int p = lane & 15;       // dim octet
    float acc[8] = {};
    #pragma unroll 2
    for (int j = beg + g; j < end; j += 4) {
        int s = col[j];
        uint4 v = *(const uint4*)&X[(size_t)s * HD + p * 8];
        acc[0] += bf_lo(v.x); acc[1] += bf_hi(v.x);
        acc[2] += bf_lo(v.y); acc[3] += bf_hi(v.y);
        acc[4] += bf_lo(v.z); acc[5] += bf_hi(v.z);
        acc[6] += bf_lo(v.w); acc[7] += bf_hi(v.w);
    }
    #pragma unroll
    for (int k = 0; k < 8; ++k) {
        acc[k] += __shfl_xor(acc[k], 16, 64);
        acc[k] += __shfl_xor(acc[k], 32, 64);
    }
    if (g == 0) {
        float inv = degInv[w];
        uint ow[4];
        #pragma unroll
        for (int k = 0; k < 4; ++k) {
            float2 vv = {acc[2 * k] * inv, acc[2 * k + 1] * inv};
            union { __hip_bfloat162 h; uint u; } cv;
            cv.h = __float22bfloat162_rn(vv);
            ow[k] = cv.u;
        }
        *(uint4*)&out[(size_t)w * HD + p * 8] = make_uint4(ow[0], ow[1], ow[2], ow[3]);
    }
}

__global__ __launch_bounds__(256) void agg_kernel(const __hip_bfloat16* __restrict__ X,
                                                  const int* __restrict__ row_ptr,
                                                  const int* __restrict__ col,
                                                  const float* __restrict__ degInv,
                                                  __hip_bfloat16* __restrict__ out) {
    agg_body(X, row_ptr, col, degInv, out, blockIdx.x);
}

// ---------------- pool body (256 thr: two 16-node halves, run-merged atomics) ----------------

__device__ __forceinline__ void pool_body(const __hip_bfloat16* __restrict__ h,
                                          const int* __restrict__ batch,
                                          float* __restrict__ p, int n0) {
    __shared__ int bsh[32];
    int t = threadIdx.x;
    if (t < 32) bsh[t] = (n0 + t < N_NODES) ? batch[n0 + t] : -1;
    __syncthreads();
    int tt = t & 127;
    int half = t >> 7;
    int r0 = half * 16;
    float run = 0.f;
    int gprev = bsh[r0];
    for (int r = r0; r < r0 + 16; ++r) {
        int n = n0 + r;
        if (n >= N_NODES) break;
        int g = bsh[r];
        float v = __bfloat162float(h[(size_t)n * HD + tt]);
        if (g != gprev) {
            atomicAdd(&p[gprev * HD + tt], run);
            run = 0.f;
            gprev = g;
        }
        run += v;
    }
    if (gprev >= 0) atomicAdd(&p[gprev * HD + tt], run);
}

__global__ __launch_bounds__(256) void pool_kernel(const __hip_bfloat16* __restrict__ h,
                                                   const int* __restrict__ batch,
                                                   float* __restrict__ p) {
    pool_body(h, batch, p, blockIdx.x * 32);
}

// ---------------- merged agg + pool dispatch (pool rides along on agg3) ----------------

__global__ __launch_bounds__(256) void agg_pool_kernel(const __hip_bfloat16* __restrict__ X,
                                                       const int* __restrict__ row_ptr,
                                                       const int* __restrict__ col,
                                                       const float* __restrict__ degInv,
                                                       __hip_bfloat16* __restrict__ out,
                                                       const int* __restrict__ batch,
                                                       float* __restrict__ p) {
    int b = blockIdx.x;
    if (b < AGG_BLKS) {
        agg_body(X, row_ptr, col, degInv, out, b);
    } else {
        pool_body(X, batch, p, (b - AGG_BLKS) * 32);
    }
}

// ---------------- dual-matmul via MFMA: out = relu([A1|A2]@Bp + b) ----------------

__global__ __launch_bounds__(256) void gemm_mfma_kernel(
        const __hip_bfloat16* __restrict__ A1, const __hip_bfloat16* __restrict__ A2,
        const __hip_bfloat16* __restrict__ Bp, const float* __restrict__ bias,
        __hip_bfloat16* __restrict__ out) {
    int lane = threadIdx.x & 63;
    int wave = threadIdx.x >> 6;
    int row0 = blockIdx.x * 64 + wave * 16;
    int arow = row0 + (lane & 15);
    int arow_c = min(arow, N_NODES - 1);
    int kb = (lane >> 4) << 3;
    f32x4 acc[8] = {};
    const bf16x8* __restrict__ Bp8 = (const bf16x8*)Bp;
    #pragma unroll
    for (int kk = 0; kk < 8; ++kk) {
        const __hip_bfloat16* __restrict__ As = (kk < 4) ? A1 : A2;
        int k0 = (kk & 3) * 32 + kb;
        bf16x8 af = *(const bf16x8*)&As[(size_t)arow_c * HD + k0];
        #pragma unroll
        for (int n = 0; n < 8; ++n) {
            bf16x8 bf = Bp8[(kk * 8 + n) * 64 + lane];
            acc[n] = __builtin_amdgcn_mfma_f32_16x16x32_bf16(af, bf, acc[n], 0, 0, 0);
        }
    }
    int crow0 = row0 + ((lane >> 4) << 2);
    int ccol = lane & 15;
    #pragma unroll
    for (int n = 0; n < 8; ++n) {
        int c = n * 16 + ccol;
        float bv = bias[c];
        #pragma unroll
        for (int i = 0; i < 4; ++i) {
            int row = crow0 + i;
            if (row < N_NODES) {
                float v = acc[n][i] + bv;
                out[(size_t)row * HD + c] = __float2bfloat16(fmaxf(v, 0.f));
            }
        }
    }
}

// ---------------- fused h2-GEMM + JK linear (R8-proven: 4 self-contained waves) ----------------

__global__ __launch_bounds__(256) void gemm2jk_kernel(
        const __hip_bfloat16* __restrict__ A, const __hip_bfloat16* __restrict__ H1,
        const __hip_bfloat16* __restrict__ BpS, const float* __restrict__ b2,
        const __hip_bfloat16* __restrict__ BpJ, const float* __restrict__ bjk,
        __hip_bfloat16* __restrict__ out) {
    __shared__ __hip_bfloat16 As[64][LDSP];
    int lane = threadIdx.x & 63;
    int wave = threadIdx.x >> 6;
    int row0 = blockIdx.x * 64 + wave * 16;
    int arow_c = min(row0 + (lane & 15), N_NODES - 1);
    int lrow = wave * 16 + (lane & 15);
    int kb = (lane >> 4) << 3;
    const bf16x8* __restrict__ BpS8 = (const bf16x8*)BpS;
    const bf16x8* __restrict__ BpJ8 = (const bf16x8*)BpJ;

    // phase B: h2 tile = relu(A@Wl2 + H1@Wr2 + b2)
    f32x4 acc[8] = {};
    #pragma unroll
    for (int kk = 0; kk < 8; ++kk) {
        const __hip_bfloat16* __restrict__ Asrc = (kk < 4) ? A : H1;
        int k0 = (kk & 3) * 32 + kb;
        bf16x8 af = *(const bf16x8*)&Asrc[(size_t)arow_c * HD + k0];
        #pragma unroll
        for (int n = 0; n < 8; ++n) {
            bf16x8 bf = BpS8[(kk * 8 + n) * 64 + lane];
            acc[n] = __builtin_amdgcn_mfma_f32_16x16x32_bf16(af, bf, acc[n], 0, 0, 0);
        }
    }
    // phase C: stash h2 into this wave's own LDS rows
    int crl0 = wave * 16 + ((lane >> 4) << 2);
    int ccol = lane & 15;
    #pragma unroll
    for (int n = 0; n < 8; ++n) {
        int c = n * 16 + ccol;
        float bv = b2[c];
        #pragma unroll
        for (int i = 0; i < 4; ++i) {
            float v = fmaxf(acc[n][i] + bv, 0.f);
            As[crl0 + i][c] = __float2bfloat16(v);
        }
    }
    // phase D: JK GEMM (k<128: H1 self from global; k>=128: h2 from LDS)
    f32x4 acc2[8] = {};
    #pragma unroll
    for (int kk = 0; kk < 8; ++kk) {
        int k0 = (kk & 3) * 32 + kb;
        bf16x8 af = (kk < 4) ? *(const bf16x8*)&H1[(size_t)arow_c * HD + k0]
                             : *(const bf16x8*)&As[lrow][k0];
        #pragma unroll
        for (int n = 0; n < 8; ++n) {
            bf16x8 bf = BpJ8[(kk * 8 + n) * 64 + lane];
            acc2[n] = __builtin_amdgcn_mfma_f32_16x16x32_bf16(af, bf, acc2[n], 0, 0, 0);
        }
    }
    int crow0 = row0 + ((lane >> 4) << 2);
    #pragma unroll
    for (int n = 0; n < 8; ++n) {
        int c = n * 16 + ccol;
        float bv = bjk[c];
        #pragma unroll
        for (int i = 0; i < 4; ++i) {
            int row = crow0 + i;
            if (row < N_NODES) {
                float v = acc2[n][i] + bv;
                out[(size_t)row * HD + c] = __float2bfloat16(fmaxf(v, 0.f));
            }
        }
    }
}

// ---------------- head: BN + MLP + softmax ----------------

__global__ void head_kernel(const float* __restrict__ p0, const float* __restrict__ p1,
                            const float* __restrict__ gamma, const float* __restrict__ beta,
                            const float* __restrict__ rm, const float* __restrict__ rv,
                            const float* __restrict__ W1, const float* __restrict__ b1,
                            const float* __restrict__ W2, const float* __restrict__ b2,
                            float* __restrict__ out) {
    __shared__ float xb[256];
    __shared__ float hh[128];
    __shared__ float oo[10];
    int g = blockIdx.x, t = threadIdx.x;  // 128 threads
    {
        float v0 = p0[g * HD + t];
        float v1 = p1[g * HD + t];
        int d1 = t + 128;
        xb[t]  = (v0 - rm[t])  * rsqrtf(rv[t]  + 1e-5f) * gamma[t]  + beta[t];
        xb[d1] = (v1 - rm[d1]) * rsqrtf(rv[d1] + 1e-5f) * gamma[d1] + beta[d1];
    }
    __syncthreads();
    float acc = b1[t];
    for (int d = 0; d < 256; ++d) acc += xb[d] * W1[d * HD + t];
    hh[t] = fmaxf(acc, 0.f);
    __syncthreads();
    if (t < 10) {
        float o = b2[t];
        for (int d = 0; d < 128; ++d) o += hh[d] * W2[d * 10 + t];
        oo[t] = o;
    }
    __syncthreads();
    if (t < 10) {
        float m = oo[0];
        for (int c = 1; c < 10; ++c) m = fmaxf(m, oo[c]);
        float sum = 0.f;
        for (int c = 0; c < 10; ++c) sum += expf(oo[c] - m);
        out[g * 10 + t] = expf(oo[t] - m) / sum;
    }
}

// ---------------- launcher ----------------

extern "C" void kernel_launch(void* const* d_in, const int* in_sizes, int n_in,
                              void* d_out, int out_size, void* d_ws, size_t ws_size,
                              hipStream_t stream) {
    const float* x     = (const float*)d_in[0];
    const int*   ei    = (const int*)d_in[1];
    const int*   batch = (const int*)d_in[2];
    const int*   src = ei;
    const int*   dst = ei + N_EDGES;

    const float* b0_Wl1 = (const float*)d_in[4];
    const float* b0_Wr1 = (const float*)d_in[5];
    const float* b0_b1  = (const float*)d_in[6];
    const float* b0_Wl2 = (const float*)d_in[7];
    const float* b0_Wr2 = (const float*)d_in[8];
    const float* b0_b2  = (const float*)d_in[9];
    const float* b0_Wlin = (const float*)d_in[10];
    const float* b0_blin = (const float*)d_in[11];
    const float* b1_Wl1 = (const float*)d_in[12];
    const float* b1_Wr1 = (const float*)d_in[13];
    const float* b1_b1  = (const float*)d_in[14];
    const float* b1_Wl2 = (const float*)d_in[15];
    const float* b1_Wr2 = (const float*)d_in[16];
    const float* b1_b2  = (const float*)d_in[17];
    const float* b1_Wlin = (const float*)d_in[18];
    const float* b1_blin = (const float*)d_in[19];
    const float* bn_gamma = (const float*)d_in[20];
    const float* bn_beta  = (const float*)d_in[21];
    const float* bn_rm    = (const float*)d_in[22];
    const float* bn_rv    = (const float*)d_in[23];
    const float* lin1_W = (const float*)d_in[24];
    const float* lin1_b = (const float*)d_in[25];
    const float* lin2_W = (const float*)d_in[26];
    const float* lin2_b = (const float*)d_in[27];

    float* out = (float*)d_out;

    char* ws = (char*)d_ws;
    size_t off = 0;
    auto alloc = [&](size_t bytes) { void* p = ws + off; off += (bytes + 255) & ~size_t(255); return p; };
    int* histG      = (int*)alloc((size_t)NBA * NBUCKET * 4);
    int* offsG      = (int*)alloc((size_t)NBUCKET * OFFS_LD * 4);
    int* bucket_tot = (int*)alloc(NBUCKET * 4);
    uint* packed    = (uint*)alloc((size_t)N_EDGES * 4);
    int* col        = (int*)alloc((size_t)N_EDGES * 4);
    int* row_ptr    = (int*)alloc((N_NODES + 1) * 4);
    float* degInv   = (float*)alloc((size_t)N_NODES * 4);
    __hip_bfloat16* Xb = (__hip_bfloat16*)alloc((size_t)N_NODES * HD * 2);
    __hip_bfloat16* A  = (__hip_bfloat16*)alloc((size_t)N_NODES * HD * 2);
    __hip_bfloat16* B  = (__hip_bfloat16*)alloc((size_t)N_NODES * HD * 2);
    __hip_bfloat16* D  = (__hip_bfloat16*)alloc((size_t)N_NODES * HD * 2);
    __hip_bfloat16* Bpack = (__hip_bfloat16*)alloc(6 * 32768 * 2);
    float* p0 = (float*)alloc(NG * HD * 4);
    float* p1 = (float*)alloc(NG * HD * 4);   // contiguous after p0 (256-aligned: NG*HD*4 = 131072)
    (void)ws_size; (void)n_in; (void)in_sizes; (void)out_size;

    // ---- fused pre: hist + cast + pack + zero(p0,p1) in ONE dispatch ----
    fused_pre_kernel<<<PRE_HIST + PRE_CAST + PRE_PACK + PRE_ZERO, 256, 0, stream>>>(
        dst, histG, x, Xb,
        b0_Wl1, b0_Wr1, b0_Wl2, b0_Wr2, b0_Wlin, b0_Wlin + 128 * HD,
        b1_Wl1, b1_Wr1, b1_Wl2, b1_Wr2, b1_Wlin, b1_Wlin + 128 * HD,
        Bpack, p0);
    scanb_kernel<<<NBUCKET, 256, 0, stream>>>(histG, offsG, bucket_tot);
    scatter_kernel<<<NBA, 256, 0, stream>>>(src, dst, bucket_tot, offsG, packed);
    csr_bucket_kernel<<<NBUCKET, 256, 0, stream>>>(packed, bucket_tot, row_ptr, degInv, col);

    const int GEMM_B = (N_NODES + 63) / 64;

    __hip_bfloat16* Bp0 = Bpack + 0 * 32768;
    __hip_bfloat16* Bp1 = Bpack + 1 * 32768;
    __hip_bfloat16* Bp2 = Bpack + 2 * 32768;
    __hip_bfloat16* Bp3 = Bpack + 3 * 32768;
    __hip_bfloat16* Bp4 = Bpack + 4 * 32768;
    __hip_bfloat16* Bp5 = Bpack + 5 * 32768;

    // block 0
    agg_kernel<<<AGG_BLKS, 256, 0, stream>>>(Xb, row_ptr, col, degInv, A);
    gemm_mfma_kernel<<<GEMM_B, 256, 0, stream>>>(A, Xb, Bp0, b0_b1, B);            // h1
    agg_kernel<<<AGG_BLKS, 256, 0, stream>>>(B, row_ptr, col, degInv, A);
    gemm2jk_kernel<<<GEMM_B, 256, 0, stream>>>(A, B, Bp1, b0_b2, Bp2, b0_blin, D); // h2+JK
    // block 1 (agg3 carries pool#1 for D -> p0)
    agg_pool_kernel<<<AGG_BLKS + POOL_BLKS, 256, 0, stream>>>(D, row_ptr, col, degInv, A,
                                                              batch, p0);
    gemm_mfma_kernel<<<GEMM_B, 256, 0, stream>>>(A, D, Bp3, b1_b1, B);             // h1
    agg_kernel<<<AGG_BLKS, 256, 0, stream>>>(B, row_ptr, col, degInv, A);
    gemm2jk_kernel<<<GEMM_B, 256, 0, stream>>>(A, B, Bp4, b1_b2, Bp5, b1_blin, D); // h2+JK
    pool_kernel<<<POOL_BLKS, 256, 0, stream>>>(D, batch, p1);
    // head
    head_kernel<<<NG, HD, 0, stream>>>(p0, p1, bn_gamma, bn_beta, bn_rm, bn_rv,
                                       lin1_W, lin1_b, lin2_W, lin2_b, out);
}